// Round 8
// baseline (2062.440 us; speedup 1.0000x reference)
//
#include <hip/hip_runtime.h>
#include <stdint.h>

// Problem sizes (fixed by reference)
#define NB   64
#define NIN  512
#define NHID 1024
#define NOUT 512
#define NT   1024

#define LSTRIDE 128   // u16 entries per (b,t) list, sentinel-padded to FULL length
// fc1 tile: 32 hidden cols, pitch 32 dwords; fc2 tile: 16 out cols, pitch 16.
// Both tiles = 65792 B -> 2 blocks/CU -> 2 waves/SIMD (the round goal).

// Loihi CUBA constants (exact in fp32)
#define A_I   0.75f
#define A_V   0.96875f
#define WSC   64.0f
#define THETA 5120.0f

typedef uint32_t u32x4 __attribute__((ext_vector_type(4)));

// Un-sinkable prefetch: real global_load issued HERE (volatile asm). The
// matching s_waitcnt join takes the destination registers as "+v" operands,
// so later uses are data-ordered after the wait; volatile<->volatile order
// keeps the loads at the issue point. (Validated round-5 machinery, verbatim.)
#define GL4(DST, PTR, OFF) \
  asm volatile("global_load_dwordx4 %0, %1, off offset:" OFF : "=v"(DST) : "v"(PTR))
#define GL1(DST, PTR) \
  asm volatile("global_load_dword %0, %1, off" : "=v"(DST) : "v"(PTR))

#define PREFETCH16(RT, LP, CW, CP) do {                                         \
    GL1(CW, CP);                                                                \
    GL4(RT[0],  LP, "0");   GL4(RT[1],  LP, "16");                              \
    GL4(RT[2],  LP, "32");  GL4(RT[3],  LP, "48");                              \
    GL4(RT[4],  LP, "64");  GL4(RT[5],  LP, "80");                              \
    GL4(RT[6],  LP, "96");  GL4(RT[7],  LP, "112");                             \
    GL4(RT[8],  LP, "128"); GL4(RT[9],  LP, "144");                             \
    GL4(RT[10], LP, "160"); GL4(RT[11], LP, "176");                             \
    GL4(RT[12], LP, "192"); GL4(RT[13], LP, "208");                             \
    GL4(RT[14], LP, "224"); GL4(RT[15], LP, "240");                             \
  } while (0)

#define WAITJOIN16(RT, CW)                                                      \
    asm volatile("s_waitcnt vmcnt(0)"                                           \
      : "+v"(RT[0]),  "+v"(RT[1]),  "+v"(RT[2]),  "+v"(RT[3]),                  \
        "+v"(RT[4]),  "+v"(RT[5]),  "+v"(RT[6]),  "+v"(RT[7]),                  \
        "+v"(RT[8]),  "+v"(RT[9]),  "+v"(RT[10]), "+v"(RT[11]),                 \
        "+v"(RT[12]), "+v"(RT[13]), "+v"(RT[14]), "+v"(RT[15]), "+v"(CW)        \
      :: "memory")

// ---------------------------------------------------------------------------
// K1: binarize x (B,Nin,T) fp32 -> bitmask bits1[b][t][iw] (u32), coalesced.
// ---------------------------------------------------------------------------
__global__ void __launch_bounds__(256) k_bits1(const float* __restrict__ x,
                                               uint32_t* __restrict__ bits1) {
  int blk = blockIdx.x;          // b*64 + iw*4 + tc
  int b  = blk >> 6;
  int iw = (blk >> 2) & 15;
  int tc = blk & 3;
  int t  = tc * 256 + threadIdx.x;
  const float* xp = x + ((size_t)(b * NIN + iw * 32)) * NT + t;
  uint32_t w = 0;
#pragma unroll
  for (int j = 0; j < 32; ++j) {
    float v = xp[(size_t)j * NT];
    if (v > 0.5f) w |= (1u << j);
  }
  bits1[((size_t)b * NT + t) * 16 + iw] = w;
}

// ---------------------------------------------------------------------------
// Extract per-(b,t) ascending index lists, PRE-SCALED by <<shift (consumer's
// LDS dword index = val + lane/col). cnt stores the GROUP count ceil(c/16).
// Full LSTRIDE sentinel-padded (sentinel maps to the zeroed LDS row; +0.0f
// adds are bit-neutral).
// ---------------------------------------------------------------------------
__global__ void __launch_bounds__(256) k_extract(const uint64_t* __restrict__ bits,
                                                 uint32_t* __restrict__ cnt,
                                                 uint16_t* __restrict__ list,
                                                 int words, int sentinel_scaled,
                                                 int shift) {
  int gid = blockIdx.x * 256 + threadIdx.x;   // = b*NT + t
  const uint64_t* wp = bits + (size_t)gid * words;
  uint16_t* lp = list + (size_t)gid * LSTRIDE;
  int c = 0;
  for (int w = 0; w < words; ++w) {
    uint64_t v = wp[w];
    while (v) {
      int j = __builtin_ctzll(v);
      v &= v - 1;
      if (c < LSTRIDE) lp[c] = (uint16_t)(((w << 6) + j) << shift);
      ++c;
    }
  }
  if (c > LSTRIDE) c = LSTRIDE;
  cnt[gid] = (uint32_t)((c + 15) >> 4);       // group count
  int cp = c;
  if (cp & 1) { lp[cp] = (uint16_t)sentinel_scaled; ++cp; }
  uint32_t s2 = (uint32_t)sentinel_scaled * 0x10001u;
  uint32_t* lp32 = (uint32_t*)lp;
  for (int k = cp >> 1; k < LSTRIDE / 2; ++k) lp32[k] = s2;
}

// ---------------------------------------------------------------------------
// K-warm: pull one XCD's list+cnt slice into its L2 after the producer
// extract (consumer swizzle: xcd = blockIdx&7 owns batches [xcd*8, xcd*8+8)).
// Read-only + data-dependent (never-taken) dump write to defeat DCE.
// ---------------------------------------------------------------------------
__global__ void __launch_bounds__(256) k_warm(const uint4* __restrict__ l4,
                                              const uint4* __restrict__ c4,
                                              uint32_t* __restrict__ dump) {
  int xcd = blockIdx.x & 7, slot = blockIdx.x >> 3;   // grid 512: slot 0..63
  const uint4* p = l4 + (size_t)xcd * 131072 + (size_t)slot * 2048;
  uint4 a = make_uint4(0, 0, 0, 0);
#pragma unroll
  for (int k = 0; k < 8; ++k) {
    uint4 v = p[k * 256 + threadIdx.x];
    a.x ^= v.x; a.y ^= v.y; a.z ^= v.z; a.w ^= v.w;
  }
  if (threadIdx.x < 32) {
    uint4 v = c4[(size_t)xcd * 2048 + slot * 32 + threadIdx.x];
    a.x ^= v.x; a.y ^= v.y; a.z ^= v.z; a.w ^= v.w;
  }
  if ((a.x ^ a.y ^ a.z ^ a.w) == 0xDEADBEEFu && threadIdx.x == 0)
    dump[blockIdx.x] = a.x;
}

// Sequential single-accumulator sums: order = ascending list entries,
// bit-identical to the validated round-1/3/4/5 kernels.
#define SUM16(ACC, B) do { _Pragma("unroll") \
  for (int q_ = 0; q_ < 16; ++q_) (ACC) += (B)[q_]; } while (0)
#define SUM8(ACC, B) do { _Pragma("unroll") \
  for (int q_ = 0; q_ < 8; ++q_) (ACC) += (B)[q_]; } while (0)

// ---------------------------------------------------------------------------
// K2: fused fc1 + LIF -> spike bitmask (u32 words) bits2[b][t][hq32(0..31)].
// OCCUPANCY VARIANT of the validated round-5 body: tile = 32 hidden columns
// (64 KB + pad) -> 2 blocks/CU -> 2 waves/SIMD. Lanes 0..31 = 32 neurons;
// lanes 32..63 duplicate harmlessly (reads stay in-bounds, results masked).
// Grid 512: xcd = blk&7, slot = blk>>3; bq = (xcd<<1)|(slot&1); hq32 = slot>>1.
// Everything else (full 16-chunk asm prefetch, vmcnt(0) join, bf0/bf1
// ping-pong, ascending group sums) is byte-identical to round 5.
// ---------------------------------------------------------------------------
__global__ void __launch_bounds__(256, 2) k_fc1(const float* __restrict__ w1,
                                                const uint32_t* __restrict__ cnt1,
                                                const uint16_t* __restrict__ list1,
                                                uint32_t* __restrict__ bits2w) {
  extern __shared__ float lds[];   // NIN x 32 + 64-pad sentinel row
  int xcd = blockIdx.x & 7, slot = blockIdx.x >> 3;
  int bq = (xcd << 1) | (slot & 1);
  int hq32 = slot >> 1;            // 0..31
  int h0 = hq32 * 32;
  for (int idx = threadIdx.x; idx < NIN * 32; idx += 256) {
    int hl = idx >> 9;             // 0..31
    int i  = idx & (NIN - 1);
    lds[i * 32 + hl] = w1[(size_t)(h0 + hl) * NIN + i];
  }
  if (threadIdx.x < 64) lds[NIN * 32 + threadIdx.x] = 0.0f;  // sentinel row
  __syncthreads();

  int wid = threadIdx.x >> 6, lane = threadIdx.x & 63;
  int b = bq * 4 + wid;
  size_t bt = (size_t)b * NT;
  float cur = 0.f, vol = 0.f;
  float bf0[16], bf1[16];
  u32x4 ct[16], rt[16];
  int cntC;
  {
    const u32x4* Lp = (const u32x4*)(list1 + bt * LSTRIDE);
#pragma unroll
    for (int k = 0; k < 16; ++k) ct[k] = Lp[k];
    cntC = (int)cnt1[bt];
  }

#define FC1_LOADG(BUF, CA, CB) do {                                             \
    u32x4 ca_ = (CA), cb_ = (CB);                                               \
    BUF[0]  = lds[(ca_[0] & 0xffffu) + lane];                                   \
    BUF[1]  = lds[(ca_[0] >> 16)     + lane];                                   \
    BUF[2]  = lds[(ca_[1] & 0xffffu) + lane];                                   \
    BUF[3]  = lds[(ca_[1] >> 16)     + lane];                                   \
    BUF[4]  = lds[(ca_[2] & 0xffffu) + lane];                                   \
    BUF[5]  = lds[(ca_[2] >> 16)     + lane];                                   \
    BUF[6]  = lds[(ca_[3] & 0xffffu) + lane];                                   \
    BUF[7]  = lds[(ca_[3] >> 16)     + lane];                                   \
    BUF[8]  = lds[(cb_[0] & 0xffffu) + lane];                                   \
    BUF[9]  = lds[(cb_[0] >> 16)     + lane];                                   \
    BUF[10] = lds[(cb_[1] & 0xffffu) + lane];                                   \
    BUF[11] = lds[(cb_[1] >> 16)     + lane];                                   \
    BUF[12] = lds[(cb_[2] & 0xffffu) + lane];                                   \
    BUF[13] = lds[(cb_[2] >> 16)     + lane];                                   \
    BUF[14] = lds[(cb_[3] & 0xffffu) + lane];                                   \
    BUF[15] = lds[(cb_[3] >> 16)     + lane];                                   \
  } while (0)

  // Prologue: group 0 of t=0 into the LDS ping-pong pipeline.
  FC1_LOADG(bf0, ct[0], ct[1]);

#define FC1_BODY(T, CT, RT) do {                                                \
    const int t_ = (T);                                                         \
    const uint16_t* lp_ = list1 + (bt + t_ + 1) * LSTRIDE;                      \
    const uint32_t* cp_ = cnt1 + (bt + t_ + 1);                                 \
    uint32_t cw_;                                                               \
    PREFETCH16(RT, lp_, cw_, cp_);                                              \
    int ng_ = __builtin_amdgcn_readfirstlane(cntC);                             \
    float acc = 0.f;                                                            \
    _Pragma("unroll")                                                           \
    for (int g = 0; g < 8; ++g) {                                               \
      if (g >= ng_) break;                                                      \
      if (g + 1 < 8 && g + 1 < ng_) {                                           \
        if ((g & 1) == 0) { FC1_LOADG(bf1, CT[2*g+2], CT[2*g+3]); }             \
        else              { FC1_LOADG(bf0, CT[2*g+2], CT[2*g+3]); }             \
      }                                                                         \
      if ((g & 1) == 0) { SUM16(acc, bf0); } else { SUM16(acc, bf1); }          \
    }                                                                           \
    WAITJOIN16(RT, cw_);                                                        \
    FC1_LOADG(bf0, RT[0], RT[1]);   /* group 0 of t+1: cross-t pipeline */      \
    cur = A_I * cur + WSC * acc;                                                \
    vol = A_V * vol + cur;                                                      \
    bool s_ = vol >= THETA;                                                     \
    vol = s_ ? 0.f : vol;                                                       \
    unsigned long long m_ = __ballot(s_);                                       \
    if (lane == 0) bits2w[(bt + t_) * 32 + hq32] = (uint32_t)m_;                \
    cntC = (int)cw_;                                                            \
  } while (0)

  for (int t = 0; t < NT - 2; t += 2) {
    FC1_BODY(t, ct, rt);
    FC1_BODY(t + 1, rt, ct);
  }
  FC1_BODY(NT - 2, ct, rt);   // t = 1022 (prefetch of t=1023 is in-bounds, unused)
#undef FC1_BODY
#undef FC1_LOADG
}

// ---------------------------------------------------------------------------
// K3: fused fc2 + LIF + both delay shifts -> final fp32 spikes.
// OCCUPANCY VARIANT of the validated round-5 body: tile = 16 output columns
// (64 KB + pad) -> 2 blocks/CU. Lanes 0..15 even entries / 16..31 odd entries
// of the same 16 outputs, combined with one commutative shfl_xor(16) add
// (same even+odd 2-sum as validated); lanes 32..63 duplicate harmlessly.
// Grid 512: bq = (xcd<<1)|(slot&1); oq16 = slot>>1; o0 = oq16*16.
// Input at tau is s1[tau-1]; out[p] = spike2[p-1]; 16-t buffered 64 B stores.
// ---------------------------------------------------------------------------
__global__ void __launch_bounds__(256, 2) k_fc2(const float* __restrict__ w2,
                                                const uint32_t* __restrict__ cnt2,
                                                const uint16_t* __restrict__ list2,
                                                float* __restrict__ out) {
  extern __shared__ float lds[];   // NHID x 16 + 64-pad sentinel row
  int xcd = blockIdx.x & 7, slot = blockIdx.x >> 3;
  int bq = (xcd << 1) | (slot & 1);
  int oq16 = slot >> 1;            // 0..31
  int o0 = oq16 * 16;
  for (int idx = threadIdx.x; idx < NHID * 16; idx += 256) {
    int om = idx >> 10;            // 0..15
    int i  = idx & (NHID - 1);
    lds[i * 16 + om] = w2[(size_t)(o0 + om) * NHID + i];
  }
  if (threadIdx.x < 64) lds[NHID * 16 + threadIdx.x] = 0.0f;  // sentinel row
  __syncthreads();

  int wid = threadIdx.x >> 6, lane = threadIdx.x & 63;
  int col = lane & 15;
  int sh  = ((lane >> 4) & 1) << 4;  // 0 = even entries, 16 = odd entries
  int b = bq * 4 + wid;
  size_t bt = (size_t)b * NT;
  float* op = out + ((size_t)b * NOUT + o0 + col) * NT;

  float cur = 0.f, vol = 0.f;
  uint32_t sm = 0;
  float bf0[8], bf1[8];
  u32x4 ct[16], rt[16];
#pragma unroll
  for (int k = 0; k < 16; ++k)
    ct[k] = (u32x4){0x40004000u, 0x40004000u, 0x40004000u, 0x40004000u};
  int cntC = 0;                    // tau=0 consumes zero-padded s1[-1]

#define FC2_LOADG(BUF, CA, CB) do {                                             \
    u32x4 ca_ = (CA), cb_ = (CB);                                               \
    BUF[0] = lds[((ca_[0] >> sh) & 0xffffu) + col];                             \
    BUF[1] = lds[((ca_[1] >> sh) & 0xffffu) + col];                             \
    BUF[2] = lds[((ca_[2] >> sh) & 0xffffu) + col];                             \
    BUF[3] = lds[((ca_[3] >> sh) & 0xffffu) + col];                             \
    BUF[4] = lds[((cb_[0] >> sh) & 0xffffu) + col];                             \
    BUF[5] = lds[((cb_[1] >> sh) & 0xffffu) + col];                             \
    BUF[6] = lds[((cb_[2] >> sh) & 0xffffu) + col];                             \
    BUF[7] = lds[((cb_[3] >> sh) & 0xffffu) + col];                             \
  } while (0)

  FC2_LOADG(bf0, ct[0], ct[1]);    // sentinel rows, harmless (ng=0 at tau=0)

#define FC2_BODY(TAU, CT, RT) do {                                             \
    const int tau_ = (TAU);                                                     \
    const uint16_t* lp_ = list2 + (bt + tau_) * LSTRIDE;                        \
    const uint32_t* cp_ = cnt2 + (bt + tau_);                                   \
    uint32_t cw_;                                                               \
    PREFETCH16(RT, lp_, cw_, cp_);                                              \
    int ng_ = __builtin_amdgcn_readfirstlane(cntC);                             \
    float acc = 0.f;                                                            \
    _Pragma("unroll")                                                           \
    for (int g = 0; g < 8; ++g) {                                               \
      if (g >= ng_) break;                                                      \
      if (g + 1 < 8 && g + 1 < ng_) {                                           \
        if ((g & 1) == 0) { FC2_LOADG(bf1, CT[2*g+2], CT[2*g+3]); }             \
        else              { FC2_LOADG(bf0, CT[2*g+2], CT[2*g+3]); }             \
      }                                                                         \
      if ((g & 1) == 0) { SUM8(acc, bf0); } else { SUM8(acc, bf1); }            \
    }                                                                           \
    WAITJOIN16(RT, cw_);                                                        \
    FC2_LOADG(bf0, RT[0], RT[1]);   /* group 0 of tau+1: cross-t pipeline */    \
    acc += __shfl_xor(acc, 16, 64); /* even+odd halves, commutative */          \
    cur = A_I * cur + WSC * acc;                                                \
    vol = A_V * vol + cur;                                                      \
    bool s_ = vol >= THETA;                                                     \
    vol = s_ ? 0.f : vol;                                                       \
    int p_ = tau_ + 1;                                                          \
    if (s_) sm |= (1u << (p_ & 15));                                            \
    if ((p_ & 15) == 15) {                                                      \
      if (lane < 16) {                                                          \
        float vb[16];                                                           \
        _Pragma("unroll")                                                       \
        for (int q = 0; q < 16; ++q) vb[q] = ((sm >> q) & 1u) ? 1.0f : 0.0f;    \
        float4* dst = (float4*)(op + (p_ - 15));                                \
        dst[0] = make_float4(vb[0],  vb[1],  vb[2],  vb[3]);                    \
        dst[1] = make_float4(vb[4],  vb[5],  vb[6],  vb[7]);                    \
        dst[2] = make_float4(vb[8],  vb[9],  vb[10], vb[11]);                   \
        dst[3] = make_float4(vb[12], vb[13], vb[14], vb[15]);                   \
      }                                                                         \
      sm = 0;                                                                   \
    }                                                                           \
    cntC = (int)cw_;                                                            \
  } while (0)

  for (int tau = 0; tau < NT - 2; tau += 2) {
    FC2_BODY(tau, ct, rt);
    FC2_BODY(tau + 1, rt, ct);
  }
  FC2_BODY(NT - 2, ct, rt);   // tau = 1022 -> p = 1023, final flush
#undef FC2_BODY
#undef FC2_LOADG
}

// ---------------------------------------------------------------------------
// ws layout (bytes): bits1 u32[64K*16] @0 (4MB, reused as warm dump);
// cnt1 @4194304 (256KB); list1 u16[64K*128] @4456448 (16MB);
// bits2 u32[64K*32] @21233664 (8MB); cnt2 @29622272 (256KB);
// list2 @29884416 (16MB).
// ---------------------------------------------------------------------------
extern "C" void kernel_launch(void* const* d_in, const int* in_sizes, int n_in,
                              void* d_out, int out_size, void* d_ws, size_t ws_size,
                              hipStream_t stream) {
  const float* x  = (const float*)d_in[0];
  const float* w1 = (const float*)d_in[1];
  const float* w2 = (const float*)d_in[2];
  float* out = (float*)d_out;

  char* ws = (char*)d_ws;
  uint32_t* bits1 = (uint32_t*)(ws);
  uint32_t* cnt1  = (uint32_t*)(ws + 4194304);
  uint16_t* list1 = (uint16_t*)(ws + 4456448);
  uint32_t* bits2 = (uint32_t*)(ws + 21233664);
  uint32_t* cnt2  = (uint32_t*)(ws + 29622272);
  uint16_t* list2 = (uint16_t*)(ws + 29884416);

  const int LDS1 = (NIN * 32 + 64) * 4;    // 65792
  const int LDS2 = (NHID * 16 + 64) * 4;   // 65792
  (void)hipFuncSetAttribute((const void*)k_fc1,
      hipFuncAttributeMaxDynamicSharedMemorySize, LDS1);
  (void)hipFuncSetAttribute((const void*)k_fc2,
      hipFuncAttributeMaxDynamicSharedMemorySize, LDS2);

  k_bits1 <<<NB * 16 * 4, 256, 0, stream>>>(x, bits1);
  k_extract<<<(NB * NT) / 256, 256, 0, stream>>>((const uint64_t*)bits1, cnt1,
                                                 list1, 8, NIN << 5, 5);
  k_warm  <<<512, 256, 0, stream>>>((const uint4*)list1, (const uint4*)cnt1,
                                    bits1);
  k_fc1   <<<512, 256, LDS1, stream>>>(w1, cnt1, list1, bits2);
  k_extract<<<(NB * NT) / 256, 256, 0, stream>>>((const uint64_t*)bits2, cnt2,
                                                 list2, 16, NHID << 4, 4);
  k_warm  <<<512, 256, 0, stream>>>((const uint4*)list2, (const uint4*)cnt2,
                                    bits1);
  k_fc2   <<<512, 256, LDS2, stream>>>(w2, cnt2, list2, out);
}

// Round 9
// 1075.557 us; speedup vs baseline: 1.9176x; 1.9176x over previous
//
#include <hip/hip_runtime.h>
#include <stdint.h>

// Problem sizes (fixed by reference)
#define NB   64
#define NIN  512
#define NHID 1024
#define NOUT 512
#define NT   1024

#define LSTRIDE 128   // u16 entries per (b,t) list, sentinel-padded to FULL length

// Loihi CUBA constants (exact in fp32)
#define A_I   0.75f
#define A_V   0.96875f
#define WSC   64.0f
#define THETA 5120.0f

typedef uint32_t u32x4 __attribute__((ext_vector_type(4)));
typedef uint32_t u32x2 __attribute__((ext_vector_type(2)));

// Un-sinkable prefetch: real global_load issued HERE (volatile asm). The
// matching s_waitcnt join takes the destination registers as "+v" operands,
// so later uses are data-ordered after the wait; volatile<->volatile order
// keeps the loads at the issue point. JOINS ARE ALWAYS vmcnt(0): stores and
// compiler-emitted loads also tick vmcnt on gfx9-lineage, so counted joins
// under-wait (R7 crash root cause).
#define GL4(DST, PTR, OFF) \
  asm volatile("global_load_dwordx4 %0, %1, off offset:" OFF : "=v"(DST) : "v"(PTR))
#define GL2(DST, PTR) \
  asm volatile("global_load_dwordx2 %0, %1, off" : "=v"(DST) : "v"(PTR))

// ---------------------------------------------------------------------------
// K1: binarize x (B,Nin,T) fp32 -> bitmask bits1[b][t][iw] (u32), coalesced.
// ---------------------------------------------------------------------------
__global__ void __launch_bounds__(256) k_bits1(const float* __restrict__ x,
                                               uint32_t* __restrict__ bits1) {
  int blk = blockIdx.x;          // b*64 + iw*4 + tc
  int b  = blk >> 6;
  int iw = (blk >> 2) & 15;
  int tc = blk & 3;
  int t  = tc * 256 + threadIdx.x;
  const float* xp = x + ((size_t)(b * NIN + iw * 32)) * NT + t;
  uint32_t w = 0;
#pragma unroll
  for (int j = 0; j < 32; ++j) {
    float v = xp[(size_t)j * NT];
    if (v > 0.5f) w |= (1u << j);
  }
  bits1[((size_t)b * NT + t) * 16 + iw] = w;
}

// ---------------------------------------------------------------------------
// Extract per-(b,t) ascending index lists, PRE-SCALED by <<shift (consumer's
// LDS dword index = val + lane/col). cnt stores the GROUP count ceil(c/16).
// Full LSTRIDE sentinel-padded (sentinel maps to the zeroed LDS row; +0.0f
// adds are bit-neutral).
// ---------------------------------------------------------------------------
__global__ void __launch_bounds__(256) k_extract(const uint64_t* __restrict__ bits,
                                                 uint32_t* __restrict__ cnt,
                                                 uint16_t* __restrict__ list,
                                                 int words, int sentinel_scaled,
                                                 int shift) {
  int gid = blockIdx.x * 256 + threadIdx.x;   // = b*NT + t
  const uint64_t* wp = bits + (size_t)gid * words;
  uint16_t* lp = list + (size_t)gid * LSTRIDE;
  int c = 0;
  for (int w = 0; w < words; ++w) {
    uint64_t v = wp[w];
    while (v) {
      int j = __builtin_ctzll(v);
      v &= v - 1;
      if (c < LSTRIDE) lp[c] = (uint16_t)(((w << 6) + j) << shift);
      ++c;
    }
  }
  if (c > LSTRIDE) c = LSTRIDE;
  cnt[gid] = (uint32_t)((c + 15) >> 4);       // group count
  int cp = c;
  if (cp & 1) { lp[cp] = (uint16_t)sentinel_scaled; ++cp; }
  uint32_t s2 = (uint32_t)sentinel_scaled * 0x10001u;
  uint32_t* lp32 = (uint32_t*)lp;
  for (int k = cp >> 1; k < LSTRIDE / 2; ++k) lp32[k] = s2;
}

// Sequential single-accumulator sums: order = ascending list entries,
// bit-identical to the validated round-1/3/4/5 kernels.
#define SUM16(ACC, B) do { _Pragma("unroll") \
  for (int q_ = 0; q_ < 16; ++q_) (ACC) += (B)[q_]; } while (0)
#define SUM8(ACC, B) do { _Pragma("unroll") \
  for (int q_ = 0; q_ < 8; ++q_) (ACC) += (B)[q_]; } while (0)

// ---------------------------------------------------------------------------
// K2: fused fc1 + LIF -> spike bitmask bits2[b][t][hq] (u64).
// XCD-swizzled blocks (lists + w1 of one bq resident in one XCD's L2).
// 4 waves = 4 batches, 64 lanes = 64 hidden, tile 64 cols (128 KB).
// TWO timesteps per body: gathers for t and t+1 interleaved through a
// P/Q/R 3-buffer LDS rotation (branchless 4 groups/stream, sentinel-exact);
// lists for (t+2,t+3) prefetched via volatile global_load (16x dwordx4 +
// dwordx2 counts), joined ONCE per body with vmcnt(0). Rare gmax>4 ->
// guarded slow path reading L2 directly (before the join, drained by it).
// Per-accumulator order: ascending groups, sequential -> bit-identical.
// ---------------------------------------------------------------------------
__global__ void __launch_bounds__(256, 1) k_fc1(const float* __restrict__ w1,
                                                const uint32_t* __restrict__ cnt1,
                                                const uint16_t* __restrict__ list1,
                                                uint64_t* __restrict__ bits2) {
  extern __shared__ float lds[];   // (NIN+1) x 64
  int xcd = blockIdx.x & 7, slot = blockIdx.x >> 3;
  int bq = (xcd << 1) | (slot & 1);
  int hq = slot >> 1;
  int h0 = hq * 64;
  for (int idx = threadIdx.x; idx < NIN * 64; idx += 256) {
    int hl = idx >> 9;             // 0..63
    int i  = idx & (NIN - 1);
    lds[i * 64 + hl] = w1[(size_t)(h0 + hl) * NIN + i];
  }
  if (threadIdx.x < 64) lds[NIN * 64 + threadIdx.x] = 0.0f;  // sentinel row
  __syncthreads();

  int wid = threadIdx.x >> 6, lane = threadIdx.x & 63;
  int b = bq * 4 + wid;
  size_t bt = (size_t)b * NT;
  float cur = 0.f, vol = 0.f;
  float P[16], Q[16], R[16];
  u32x4 cA[8], cB[8], rA[8], rB[8];
  u32x2 cN, rN;

#define FC1_LOADG(BUF, CA_, CB_) do {                                           \
    u32x4 ca_ = (CA_), cb_ = (CB_);                                             \
    BUF[0]  = lds[(ca_[0] & 0xffffu) + lane];                                   \
    BUF[1]  = lds[(ca_[0] >> 16)     + lane];                                   \
    BUF[2]  = lds[(ca_[1] & 0xffffu) + lane];                                   \
    BUF[3]  = lds[(ca_[1] >> 16)     + lane];                                   \
    BUF[4]  = lds[(ca_[2] & 0xffffu) + lane];                                   \
    BUF[5]  = lds[(ca_[2] >> 16)     + lane];                                   \
    BUF[6]  = lds[(ca_[3] & 0xffffu) + lane];                                   \
    BUF[7]  = lds[(ca_[3] >> 16)     + lane];                                   \
    BUF[8]  = lds[(cb_[0] & 0xffffu) + lane];                                   \
    BUF[9]  = lds[(cb_[0] >> 16)     + lane];                                   \
    BUF[10] = lds[(cb_[1] & 0xffffu) + lane];                                   \
    BUF[11] = lds[(cb_[1] >> 16)     + lane];                                   \
    BUF[12] = lds[(cb_[2] & 0xffffu) + lane];                                   \
    BUF[13] = lds[(cb_[2] >> 16)     + lane];                                   \
    BUF[14] = lds[(cb_[3] & 0xffffu) + lane];                                   \
    BUF[15] = lds[(cb_[3] >> 16)     + lane];                                   \
  } while (0)

#define FC1_JOIN(RA, RB, RN)                                                    \
    asm volatile("s_waitcnt vmcnt(0)"                                           \
      : "+v"(RA[0]), "+v"(RA[1]), "+v"(RA[2]), "+v"(RA[3]),                     \
        "+v"(RA[4]), "+v"(RA[5]), "+v"(RA[6]), "+v"(RA[7]),                     \
        "+v"(RB[0]), "+v"(RB[1]), "+v"(RB[2]), "+v"(RB[3]),                     \
        "+v"(RB[4]), "+v"(RB[5]), "+v"(RB[6]), "+v"(RB[7]), "+v"(RN)            \
      :: "memory")

  // Prologue: lists for t=0,1 + counts (plain loads), group-0 buffers.
  {
    const u32x4* L0 = (const u32x4*)(list1 + bt * LSTRIDE);
#pragma unroll
    for (int k = 0; k < 8; ++k) { cA[k] = L0[k]; cB[k] = L0[16 + k]; }
    cN[0] = cnt1[bt]; cN[1] = cnt1[bt + 1];
  }
  FC1_LOADG(P, cA[0], cA[1]);
  FC1_LOADG(Q, cB[0], cB[1]);

#define FC1_BODY(T, CA, CB, CN, RA, RB, RN) do {                                \
    const int t_ = (T);                                                         \
    const uint16_t* lp_ = list1 + (bt + t_ + 2) * LSTRIDE;                      \
    const uint32_t* cp_ = cnt1 + (bt + t_ + 2);                                 \
    GL4(RA[0], lp_, "0");   GL4(RA[1], lp_, "16");                              \
    GL4(RA[2], lp_, "32");  GL4(RA[3], lp_, "48");                              \
    GL4(RA[4], lp_, "64");  GL4(RA[5], lp_, "80");                              \
    GL4(RA[6], lp_, "96");  GL4(RA[7], lp_, "112");                             \
    GL4(RB[0], lp_, "256"); GL4(RB[1], lp_, "272");                             \
    GL4(RB[2], lp_, "288"); GL4(RB[3], lp_, "304");                             \
    GL4(RB[4], lp_, "320"); GL4(RB[5], lp_, "336");                             \
    GL4(RB[6], lp_, "352"); GL4(RB[7], lp_, "368");                             \
    GL2(RN, cp_);                                                               \
    float accA = 0.f, accB = 0.f;                                               \
    /* branchless 4 groups per stream, 3-buffer rotation (sentinel-exact) */    \
    FC1_LOADG(R, CA[2], CA[3]);  SUM16(accA, P);                                \
    FC1_LOADG(P, CB[2], CB[3]);  SUM16(accB, Q);                                \
    FC1_LOADG(Q, CA[4], CA[5]);  SUM16(accA, R);                                \
    FC1_LOADG(R, CB[4], CB[5]);  SUM16(accB, P);                                \
    FC1_LOADG(P, CA[6], CA[7]);  SUM16(accA, Q);                                \
    FC1_LOADG(Q, CB[6], CB[7]);  SUM16(accB, R);                                \
    SUM16(accA, P);  SUM16(accB, Q);                                            \
    int ngA_ = __builtin_amdgcn_readfirstlane((int)CN[0]);                      \
    int ngB_ = __builtin_amdgcn_readfirstlane((int)CN[1]);                      \
    int gmx_ = ngA_ > ngB_ ? ngA_ : ngB_;                                       \
    if (__builtin_expect(gmx_ > 4, 0)) {   /* ~2.4% of bodies */                \
      const u32x4* LcA_ = (const u32x4*)(list1 + (bt + t_) * LSTRIDE);          \
      const u32x4* LcB_ = LcA_ + 16;                                            \
      for (int g = 4; g < gmx_; ++g) {                                          \
        if (g < ngA_) { u32x4 x0 = LcA_[2*g], x1 = LcA_[2*g+1];                 \
                        FC1_LOADG(R, x0, x1); SUM16(accA, R); }                 \
        if (g < ngB_) { u32x4 x0 = LcB_[2*g], x1 = LcB_[2*g+1];                 \
                        FC1_LOADG(R, x0, x1); SUM16(accB, R); }                 \
      }                                                                         \
    }                                                                           \
    FC1_JOIN(RA, RB, RN);                                                       \
    FC1_LOADG(P, RA[0], RA[1]);   /* group 0 of next body's streams */          \
    FC1_LOADG(Q, RB[0], RB[1]);                                                 \
    cur = A_I * cur + WSC * accA;                                               \
    vol = A_V * vol + cur;                                                      \
    bool sA_ = vol >= THETA;  vol = sA_ ? 0.f : vol;                            \
    unsigned long long mA_ = __ballot(sA_);                                     \
    cur = A_I * cur + WSC * accB;                                               \
    vol = A_V * vol + cur;                                                      \
    bool sB_ = vol >= THETA;  vol = sB_ ? 0.f : vol;                            \
    unsigned long long mB_ = __ballot(sB_);                                     \
    if (lane == 0) {                                                            \
      bits2[(bt + t_) * 16 + hq]     = mA_;                                     \
      bits2[(bt + t_ + 1) * 16 + hq] = mB_;                                     \
    }                                                                           \
  } while (0)

  // 511 bodies cover t = 0..1021 (fc2 consumes s1 only up to t=1021).
  for (int t = 0; t < 1020; t += 4) {
    FC1_BODY(t,     cA, cB, cN, rA, rB, rN);
    FC1_BODY(t + 2, rA, rB, rN, cA, cB, cN);
  }
  FC1_BODY(1020, cA, cB, cN, rA, rB, rN);
#undef FC1_BODY
#undef FC1_LOADG
#undef FC1_JOIN
}

// ---------------------------------------------------------------------------
// K3: fused fc2 + LIF + both delay shifts -> final fp32 spikes.
// Same swizzle. 4 waves = 4 batches; lanes 0..31 / 32..63 take even/odd list
// entries for the same 32 outputs, combined via one commutative shfl_xor(32)
// add (validated R1/3/4/5). TWO timesteps per body: branchless 2 groups per
// stream (hidden spike count is small), P/Q/R rotation, one 9-load prefetch
// of (L(tau+1), L(tau+2), counts) joined per body with vmcnt(0).
// Input at tau is s1[tau-1]; out[p] = spike2[p-1]; 16-p register-buffered
// 64 B stores (flush points p = 16k+15, all odd = step A; tail p=1023).
// ---------------------------------------------------------------------------
__global__ void __launch_bounds__(256, 1) k_fc2(const float* __restrict__ w2,
                                                const uint32_t* __restrict__ cnt2,
                                                const uint16_t* __restrict__ list2,
                                                float* __restrict__ out) {
  extern __shared__ float lds[];   // (NHID+1) x 32
  int xcd = blockIdx.x & 7, slot = blockIdx.x >> 3;
  int bq = (xcd << 1) | (slot & 1);
  int oq = slot >> 1;
  int o0 = oq * 32;
  for (int idx = threadIdx.x; idx < NHID * 32; idx += 256) {
    int om = idx >> 10;            // 0..31
    int i  = idx & (NHID - 1);
    lds[i * 32 + om] = w2[(size_t)(o0 + om) * NHID + i];
  }
  if (threadIdx.x < 32) lds[NHID * 32 + threadIdx.x] = 0.0f;  // sentinel row
  __syncthreads();

  int wid = threadIdx.x >> 6, lane = threadIdx.x & 63;
  int col = lane & 31;
  int sh  = (lane >> 5) << 4;      // 0 = even entries, 16 = odd entries
  int b = bq * 4 + wid;
  size_t bt = (size_t)b * NT;
  float* op = out + ((size_t)b * NOUT + o0 + col) * NT;

  float cur = 0.f, vol = 0.f;
  uint32_t sm = 0;
  float P[8], Q[8], R[8];
  u32x4 cA[4], cB[4], rA[4], rB[4];
  u32x2 cN, rN;

#define FC2_LOADG(BUF, CA_, CB_) do {                                           \
    u32x4 ca_ = (CA_), cb_ = (CB_);                                             \
    BUF[0] = lds[((ca_[0] >> sh) & 0xffffu) + col];                             \
    BUF[1] = lds[((ca_[1] >> sh) & 0xffffu) + col];                             \
    BUF[2] = lds[((ca_[2] >> sh) & 0xffffu) + col];                             \
    BUF[3] = lds[((ca_[3] >> sh) & 0xffffu) + col];                             \
    BUF[4] = lds[((cb_[0] >> sh) & 0xffffu) + col];                             \
    BUF[5] = lds[((cb_[1] >> sh) & 0xffffu) + col];                             \
    BUF[6] = lds[((cb_[2] >> sh) & 0xffffu) + col];                             \
    BUF[7] = lds[((cb_[3] >> sh) & 0xffffu) + col];                             \
  } while (0)

#define FC2_JOIN(RA, RB, RN)                                                    \
    asm volatile("s_waitcnt vmcnt(0)"                                           \
      : "+v"(RA[0]), "+v"(RA[1]), "+v"(RA[2]), "+v"(RA[3]),                     \
        "+v"(RB[0]), "+v"(RB[1]), "+v"(RB[2]), "+v"(RB[3]), "+v"(RN)            \
      :: "memory")

#define FC2_FLUSH(PV) do {                                                      \
    if (lane < 32) {                                                            \
      float vb[16];                                                             \
      _Pragma("unroll")                                                         \
      for (int q = 0; q < 16; ++q) vb[q] = ((sm >> q) & 1u) ? 1.0f : 0.0f;      \
      float4* dst = (float4*)(op + ((PV) - 15));                                \
      dst[0] = make_float4(vb[0],  vb[1],  vb[2],  vb[3]);                      \
      dst[1] = make_float4(vb[4],  vb[5],  vb[6],  vb[7]);                      \
      dst[2] = make_float4(vb[8],  vb[9],  vb[10], vb[11]);                     \
      dst[3] = make_float4(vb[12], vb[13], vb[14], vb[15]);                     \
    }                                                                           \
  } while (0)

  // Prologue: stream A of body(0) = s1[-1] -> sentinels (ng 0);
  // stream B = L(0) (plain loads).
#pragma unroll
  for (int k = 0; k < 4; ++k)
    cA[k] = (u32x4){0x80008000u, 0x80008000u, 0x80008000u, 0x80008000u};
  {
    const u32x4* Lz = (const u32x4*)(list2 + bt * LSTRIDE);
#pragma unroll
    for (int k = 0; k < 4; ++k) cB[k] = Lz[k];
    cN[0] = 0; cN[1] = cnt2[bt];
  }
  FC2_LOADG(P, cA[0], cA[1]);   // sentinel reads, +0.0f
  FC2_LOADG(Q, cB[0], cB[1]);

#define FC2_BODY(TAU, CA, CB, CN, RA, RB, RN) do {                              \
    const int tau_ = (TAU);                                                     \
    const uint16_t* lp_ = list2 + (bt + tau_ + 1) * LSTRIDE;                    \
    const uint32_t* cp_ = cnt2 + (bt + tau_ + 1);                               \
    GL4(RA[0], lp_, "0");   GL4(RA[1], lp_, "16");                              \
    GL4(RA[2], lp_, "32");  GL4(RA[3], lp_, "48");                              \
    GL4(RB[0], lp_, "256"); GL4(RB[1], lp_, "272");                             \
    GL4(RB[2], lp_, "288"); GL4(RB[3], lp_, "304");                             \
    GL2(RN, cp_);                                                               \
    float accA = 0.f, accB = 0.f;                                               \
    FC2_LOADG(R, CA[2], CA[3]);  SUM8(accA, P);                                 \
    FC2_LOADG(P, CB[2], CB[3]);  SUM8(accB, Q);                                 \
    SUM8(accA, R);  SUM8(accB, P);                                              \
    int ngA_ = __builtin_amdgcn_readfirstlane((int)CN[0]);                      \
    int ngB_ = __builtin_amdgcn_readfirstlane((int)CN[1]);                      \
    int gmx_ = ngA_ > ngB_ ? ngA_ : ngB_;                                       \
    if (__builtin_expect(gmx_ > 2, 0)) {   /* rare: hidden rate is low */       \
      const u32x4* LsA_ = (const u32x4*)(list2 + (bt + tau_) * LSTRIDE) - 16;   \
      const u32x4* LsB_ = LsA_ + 16;                                            \
      for (int g = 2; g < gmx_; ++g) {                                          \
        if (g < ngA_) { u32x4 x0 = LsA_[2*g], x1 = LsA_[2*g+1];                 \
                        FC2_LOADG(R, x0, x1); SUM8(accA, R); }                  \
        if (g < ngB_) { u32x4 x0 = LsB_[2*g], x1 = LsB_[2*g+1];                 \
                        FC2_LOADG(R, x0, x1); SUM8(accB, R); }                  \
      }                                                                         \
    }                                                                           \
    FC2_JOIN(RA, RB, RN);                                                       \
    FC2_LOADG(P, RA[0], RA[1]);                                                 \
    FC2_LOADG(Q, RB[0], RB[1]);                                                 \
    accA += __shfl_xor(accA, 32, 64);   /* even+odd halves, commutative */      \
    cur = A_I * cur + WSC * accA;                                               \
    vol = A_V * vol + cur;                                                      \
    bool sA_ = vol >= THETA;  vol = sA_ ? 0.f : vol;                            \
    int pA_ = tau_ + 1;                                                         \
    if (sA_) sm |= 1u << (pA_ & 15);                                            \
    if ((pA_ & 15) == 15) { FC2_FLUSH(pA_); sm = 0; }                           \
    accB += __shfl_xor(accB, 32, 64);                                           \
    cur = A_I * cur + WSC * accB;                                               \
    vol = A_V * vol + cur;                                                      \
    bool sB_ = vol >= THETA;  vol = sB_ ? 0.f : vol;                            \
    int pB_ = tau_ + 2;                                                         \
    if (sB_) sm |= 1u << (pB_ & 15);                                            \
    /* (pB_ & 15) == 15 impossible: pB_ even, flush points are odd */           \
  } while (0)

  // 511 bodies cover tau = 0..1021; tail handles tau = 1022 (p = 1023).
  for (int tau = 0; tau < 1020; tau += 4) {
    FC2_BODY(tau,     cA, cB, cN, rA, rB, rN);
    FC2_BODY(tau + 2, rA, rB, rN, cA, cB, cN);
  }
  FC2_BODY(1020, cA, cB, cN, rA, rB, rN);
  // Tail: tau = 1022 consumes stream A of the r-generation = L(1021).
  {
    int ng_ = __builtin_amdgcn_readfirstlane((int)rN[0]);
    float accA = 0.f;
    FC2_LOADG(R, rA[2], rA[3]);
    SUM8(accA, P);                 // P preloaded from rA[0], rA[1]
    SUM8(accA, R);
    if (__builtin_expect(ng_ > 2, 0)) {
      const u32x4* Ls_ = (const u32x4*)(list2 + (bt + 1021) * LSTRIDE);
      for (int g = 2; g < ng_; ++g) {
        u32x4 x0 = Ls_[2 * g], x1 = Ls_[2 * g + 1];
        FC2_LOADG(R, x0, x1); SUM8(accA, R);
      }
    }
    accA += __shfl_xor(accA, 32, 64);
    cur = A_I * cur + WSC * accA;
    vol = A_V * vol + cur;
    bool s_ = vol >= THETA;
    if (s_) sm |= 1u << 15;        // p = 1023
    FC2_FLUSH(1023);
  }
#undef FC2_BODY
#undef FC2_LOADG
#undef FC2_JOIN
#undef FC2_FLUSH
}

// ---------------------------------------------------------------------------
// ws layout (bytes): bits1 u32[64K*16] @0 (4MB); cnt1 @4194304 (256KB);
// list1 u16[64K*128] @4456448 (16MB); bits2 u64[64K*16] @21233664 (8MB);
// cnt2 @29622272 (256KB); list2 @29884416 (16MB).
// ---------------------------------------------------------------------------
extern "C" void kernel_launch(void* const* d_in, const int* in_sizes, int n_in,
                              void* d_out, int out_size, void* d_ws, size_t ws_size,
                              hipStream_t stream) {
  const float* x  = (const float*)d_in[0];
  const float* w1 = (const float*)d_in[1];
  const float* w2 = (const float*)d_in[2];
  float* out = (float*)d_out;

  char* ws = (char*)d_ws;
  uint32_t* bits1 = (uint32_t*)(ws);
  uint32_t* cnt1  = (uint32_t*)(ws + 4194304);
  uint16_t* list1 = (uint16_t*)(ws + 4456448);
  uint64_t* bits2 = (uint64_t*)(ws + 21233664);
  uint32_t* cnt2  = (uint32_t*)(ws + 29622272);
  uint16_t* list2 = (uint16_t*)(ws + 29884416);

  const int LDS1 = (NIN + 1) * 64 * 4;    // 131328
  const int LDS2 = (NHID + 1) * 32 * 4;   // 131200
  (void)hipFuncSetAttribute((const void*)k_fc1,
      hipFuncAttributeMaxDynamicSharedMemorySize, LDS1);
  (void)hipFuncSetAttribute((const void*)k_fc2,
      hipFuncAttributeMaxDynamicSharedMemorySize, LDS2);

  k_bits1 <<<NB * 16 * 4, 256, 0, stream>>>(x, bits1);
  k_extract<<<(NB * NT) / 256, 256, 0, stream>>>((const uint64_t*)bits1, cnt1,
                                                 list1, 8, NIN << 6, 6);
  k_fc1   <<<16 * 16, 256, LDS1, stream>>>(w1, cnt1, list1, bits2);
  k_extract<<<(NB * NT) / 256, 256, 0, stream>>>((const uint64_t*)bits2, cnt2,
                                                 list2, 16, NHID << 5, 5);
  k_fc2   <<<16 * 16, 256, LDS2, stream>>>(w2, cnt2, list2, out);
}

// Round 10
// 962.944 us; speedup vs baseline: 2.1418x; 1.1169x over previous
//
#include <hip/hip_runtime.h>
#include <stdint.h>

// Problem sizes (fixed by reference)
#define NB   64
#define NIN  512
#define NHID 1024
#define NOUT 512
#define NT   1024

#define LSTRIDE 128   // u16 entries per (b,t) list, sentinel-padded to FULL length

// Loihi CUBA constants (exact in fp32)
#define A_I   0.75f
#define A_V   0.96875f
#define WSC   64.0f
#define THETA 5120.0f

typedef uint32_t u32x4 __attribute__((ext_vector_type(4)));
typedef uint32_t u32x2 __attribute__((ext_vector_type(2)));

// Un-sinkable prefetch: real global_load issued HERE (volatile asm). The
// matching s_waitcnt join takes the destination registers as "+v" operands,
// so later uses are data-ordered after the wait; volatile<->volatile order
// keeps the loads at the issue point. JOINS ARE ALWAYS vmcnt(0): stores and
// compiler-emitted loads also tick vmcnt, so counted joins under-wait.
#define GL4(DST, PTR, OFF) \
  asm volatile("global_load_dwordx4 %0, %1, off offset:" OFF : "=v"(DST) : "v"(PTR))
#define GL2(DST, PTR) \
  asm volatile("global_load_dwordx2 %0, %1, off" : "=v"(DST) : "v"(PTR))
#define GL1(DST, PTR) \
  asm volatile("global_load_dword %0, %1, off" : "=v"(DST) : "v"(PTR))

// LDS-only ordering fence (state mailbox). NOT __threadfence_block(): that
// emits vmcnt(0) too and would drain the list prefetch pipeline.
#define LDS_FENCE() asm volatile("s_waitcnt lgkmcnt(0)" ::: "memory")

// ---------------------------------------------------------------------------
// K1: binarize x (B,Nin,T) fp32 -> bitmask bits1[b][t][iw] (u32), coalesced.
// ---------------------------------------------------------------------------
__global__ void __launch_bounds__(256) k_bits1(const float* __restrict__ x,
                                               uint32_t* __restrict__ bits1) {
  int blk = blockIdx.x;          // b*64 + iw*4 + tc
  int b  = blk >> 6;
  int iw = (blk >> 2) & 15;
  int tc = blk & 3;
  int t  = tc * 256 + threadIdx.x;
  const float* xp = x + ((size_t)(b * NIN + iw * 32)) * NT + t;
  uint32_t w = 0;
#pragma unroll
  for (int j = 0; j < 32; ++j) {
    float v = xp[(size_t)j * NT];
    if (v > 0.5f) w |= (1u << j);
  }
  bits1[((size_t)b * NT + t) * 16 + iw] = w;
}

// ---------------------------------------------------------------------------
// Extract per-(b,t) ascending index lists, PRE-SCALED by <<shift (consumer's
// LDS dword index = val + lane/col). cnt stores the GROUP count ceil(c/16).
// Full LSTRIDE sentinel-padded (sentinel maps to the zeroed LDS row; +0.0f
// adds are bit-neutral).
// ---------------------------------------------------------------------------
__global__ void __launch_bounds__(256) k_extract(const uint64_t* __restrict__ bits,
                                                 uint32_t* __restrict__ cnt,
                                                 uint16_t* __restrict__ list,
                                                 int words, int sentinel_scaled,
                                                 int shift) {
  int gid = blockIdx.x * 256 + threadIdx.x;   // = b*NT + t
  const uint64_t* wp = bits + (size_t)gid * words;
  uint16_t* lp = list + (size_t)gid * LSTRIDE;
  int c = 0;
  for (int w = 0; w < words; ++w) {
    uint64_t v = wp[w];
    while (v) {
      int j = __builtin_ctzll(v);
      v &= v - 1;
      if (c < LSTRIDE) lp[c] = (uint16_t)(((w << 6) + j) << shift);
      ++c;
    }
  }
  if (c > LSTRIDE) c = LSTRIDE;
  cnt[gid] = (uint32_t)((c + 15) >> 4);       // group count
  int cp = c;
  if (cp & 1) { lp[cp] = (uint16_t)sentinel_scaled; ++cp; }
  uint32_t s2 = (uint32_t)sentinel_scaled * 0x10001u;
  uint32_t* lp32 = (uint32_t*)lp;
  for (int k = cp >> 1; k < LSTRIDE / 2; ++k) lp32[k] = s2;
}

// Sequential single-accumulator sums: order = ascending list entries,
// bit-identical to the validated round-1/3/4/5/9 kernels.
#define SUM16(ACC, B) do { _Pragma("unroll") \
  for (int q_ = 0; q_ < 16; ++q_) (ACC) += (B)[q_]; } while (0)
#define SUM8(ACC, B) do { _Pragma("unroll") \
  for (int q_ = 0; q_ < 8; ++q_) (ACC) += (B)[q_]; } while (0)

// ---------------------------------------------------------------------------
// K2: fused fc1 + LIF -> spike bitmask bits2[b][t][hq] (u64).
// TIME-PAIRED WAVES: block = 512 threads = 8 waves = 4 chains x 2 parities.
// Chain c = wave&3 (batch bq*4+c, all 64 lanes = 64 hidden cols, EXACTLY the
// validated R9 per-wave geometry); parity = wave>>2 (even/odd timesteps).
// Each wave gathers its own timestep's FULL list (per-neuron ascending sum,
// unchanged); the serial LIF state (cur,vol) hops between partner waves via
// an LDS mailbox: write state -> lgkmcnt(0) -> write flag=t; partner spins
// on flag >= t-1 (monotonic), fences, reads state. No __syncthreads in the
// loop, so partner waves' gathers overlap and hide each other's stalls.
// Lists prefetched per body via volatile global_load, joined with vmcnt(0).
// ---------------------------------------------------------------------------
__global__ void __launch_bounds__(512, 2) k_fc1(const float* __restrict__ w1,
                                                const uint32_t* __restrict__ cnt1,
                                                const uint16_t* __restrict__ list1,
                                                uint64_t* __restrict__ bits2) {
  extern __shared__ float lds[];   // tile 513x64 | state [2][4][64]f2 | flags [2][4]
  int xcd = blockIdx.x & 7, slot = blockIdx.x >> 3;
  int bq = (xcd << 1) | (slot & 1);
  int hq = slot >> 1;
  int h0 = hq * 64;
  for (int idx = threadIdx.x; idx < NIN * 64; idx += 512) {
    int hl = idx >> 9;             // 0..63
    int i  = idx & (NIN - 1);
    lds[i * 64 + hl] = w1[(size_t)(h0 + hl) * NIN + i];
  }
  if (threadIdx.x < 64) lds[NIN * 64 + threadIdx.x] = 0.0f;  // sentinel row
  float* stbase = lds + 32832;               // 1024 dwords of state
  int*   flbase = (int*)(lds + 32832 + 1024);
  stbase[threadIdx.x]       = 0.0f;          // zero all state (2x512 dwords)
  stbase[512 + threadIdx.x] = 0.0f;
  if (threadIdx.x < 4) {
    flbase[threadIdx.x]     = -2;            // even-par flags: t=-2 (none)
    flbase[4 + threadIdx.x] = -1;            // odd-par flags: state(-1)=zeros
  }
  __syncthreads();

  int wid = threadIdx.x >> 6, lane = threadIdx.x & 63;
  int c   = wid & 3;               // chain (batch)
  int par = wid >> 2;              // 0 = even t, 1 = odd t
  int b = bq * 4 + c;
  size_t bt = (size_t)b * NT;
  float2* stMine = (float2*)(stbase + par * 512 + c * 128);
  float2* stPart = (float2*)(stbase + (1 - par) * 512 + c * 128);
  volatile int* flMine = flbase + par * 4 + c;
  volatile int* flPart = flbase + (1 - par) * 4 + c;

  float P[16], Q[16], R[16];
  u32x4 ct[8], rt[8];
  int cntC;
  {
    const u32x4* Lp = (const u32x4*)(list1 + (bt + par) * LSTRIDE);
#pragma unroll
    for (int k = 0; k < 8; ++k) ct[k] = Lp[k];
    cntC = (int)cnt1[bt + par];
  }

#define FC1_LOADG(BUF, CA_, CB_) do {                                           \
    u32x4 ca_ = (CA_), cb_ = (CB_);                                             \
    BUF[0]  = lds[(ca_[0] & 0xffffu) + lane];                                   \
    BUF[1]  = lds[(ca_[0] >> 16)     + lane];                                   \
    BUF[2]  = lds[(ca_[1] & 0xffffu) + lane];                                   \
    BUF[3]  = lds[(ca_[1] >> 16)     + lane];                                   \
    BUF[4]  = lds[(ca_[2] & 0xffffu) + lane];                                   \
    BUF[5]  = lds[(ca_[2] >> 16)     + lane];                                   \
    BUF[6]  = lds[(ca_[3] & 0xffffu) + lane];                                   \
    BUF[7]  = lds[(ca_[3] >> 16)     + lane];                                   \
    BUF[8]  = lds[(cb_[0] & 0xffffu) + lane];                                   \
    BUF[9]  = lds[(cb_[0] >> 16)     + lane];                                   \
    BUF[10] = lds[(cb_[1] & 0xffffu) + lane];                                   \
    BUF[11] = lds[(cb_[1] >> 16)     + lane];                                   \
    BUF[12] = lds[(cb_[2] & 0xffffu) + lane];                                   \
    BUF[13] = lds[(cb_[2] >> 16)     + lane];                                   \
    BUF[14] = lds[(cb_[3] & 0xffffu) + lane];                                   \
    BUF[15] = lds[(cb_[3] >> 16)     + lane];                                   \
  } while (0)

#define FC1_JOIN(RT, CW)                                                        \
    asm volatile("s_waitcnt vmcnt(0)"                                           \
      : "+v"(RT[0]), "+v"(RT[1]), "+v"(RT[2]), "+v"(RT[3]),                     \
        "+v"(RT[4]), "+v"(RT[5]), "+v"(RT[6]), "+v"(RT[7]), "+v"(CW)            \
      :: "memory")

#define FC1_BODY(T, CT, RT) do {                                                \
    const int t_ = (T);                                                         \
    int tp_ = t_ + 2;  if (tp_ > NT - 1) tp_ = NT - 1;                          \
    const uint16_t* lp_ = list1 + (bt + tp_) * LSTRIDE;                         \
    const uint32_t* cp_ = cnt1 + (bt + tp_);                                    \
    uint32_t cw_;                                                               \
    GL1(cw_, cp_);                                                              \
    GL4(RT[0], lp_, "0");   GL4(RT[1], lp_, "16");                              \
    GL4(RT[2], lp_, "32");  GL4(RT[3], lp_, "48");                              \
    GL4(RT[4], lp_, "64");  GL4(RT[5], lp_, "80");                              \
    GL4(RT[6], lp_, "96");  GL4(RT[7], lp_, "112");                             \
    int ng_ = __builtin_amdgcn_readfirstlane(cntC);                             \
    float acc = 0.f;                                                            \
    /* branchless 4 groups, 3-buffer rotation (sentinel-exact, ascending) */    \
    FC1_LOADG(P, CT[0], CT[1]);                                                 \
    FC1_LOADG(Q, CT[2], CT[3]);                                                 \
    SUM16(acc, P);                                                              \
    FC1_LOADG(R, CT[4], CT[5]);                                                 \
    SUM16(acc, Q);                                                              \
    FC1_LOADG(P, CT[6], CT[7]);                                                 \
    SUM16(acc, R);                                                              \
    SUM16(acc, P);                                                              \
    if (__builtin_expect(ng_ > 4, 0)) {   /* ~2.4% of timesteps */              \
      const u32x4* Lc_ = (const u32x4*)(list1 + (bt + t_) * LSTRIDE);           \
      for (int g = 4; g < ng_; ++g) {                                           \
        u32x4 x0 = Lc_[2 * g], x1 = Lc_[2 * g + 1];                             \
        FC1_LOADG(R, x0, x1);                                                   \
        SUM16(acc, R);                                                          \
      }                                                                         \
    }                                                                           \
    FC1_JOIN(RT, cw_);                                                          \
    /* LIF: state arrives from partner wave (t-1), result goes back */          \
    {                                                                           \
      int want_ = t_ - 1;                                                       \
      for (;;) {                                                                \
        int fl_ = *flPart;                                                      \
        if (fl_ >= want_) break;                                                \
        __builtin_amdgcn_s_sleep(1);                                            \
      }                                                                         \
      LDS_FENCE();                                                              \
      float2 sv_ = stPart[lane];                                                \
      float cur_ = A_I * sv_.x + WSC * acc;                                     \
      float vol_ = A_V * sv_.y + cur_;                                          \
      bool s_ = vol_ >= THETA;                                                  \
      vol_ = s_ ? 0.f : vol_;                                                   \
      stMine[lane] = make_float2(cur_, vol_);                                   \
      LDS_FENCE();                                                              \
      if (lane == 0) *flMine = t_;                                              \
      unsigned long long m_ = __ballot(s_);                                     \
      if (lane == 0) bits2[(bt + t_) * 16 + hq] = m_;                           \
    }                                                                           \
    cntC = (int)cw_;                                                            \
  } while (0)

  // 512 bodies per wave: even wave t = 0,2,...,1022; odd wave t = 1,3,...,1023.
  for (int k = 0; k < 256; ++k) {
    FC1_BODY(par + 4 * k,     ct, rt);
    FC1_BODY(par + 4 * k + 2, rt, ct);
  }
#undef FC1_BODY
#undef FC1_LOADG
#undef FC1_JOIN
}

// ---------------------------------------------------------------------------
// K3: fused fc2 + LIF + both delay shifts -> final fp32 spikes.
// VERBATIM validated R9 kernel. 4 waves = 4 batches; lanes 0..31 / 32..63
// take even/odd list entries for the same 32 outputs, combined via one
// commutative shfl_xor(32) add. TWO timesteps per body, P/Q/R rotation,
// one 9-load prefetch joined per body with vmcnt(0). Input at tau is
// s1[tau-1]; out[p] = spike2[p-1]; 16-p register-buffered 64 B stores.
// ---------------------------------------------------------------------------
__global__ void __launch_bounds__(256, 1) k_fc2(const float* __restrict__ w2,
                                                const uint32_t* __restrict__ cnt2,
                                                const uint16_t* __restrict__ list2,
                                                float* __restrict__ out) {
  extern __shared__ float lds[];   // (NHID+1) x 32
  int xcd = blockIdx.x & 7, slot = blockIdx.x >> 3;
  int bq = (xcd << 1) | (slot & 1);
  int oq = slot >> 1;
  int o0 = oq * 32;
  for (int idx = threadIdx.x; idx < NHID * 32; idx += 256) {
    int om = idx >> 10;            // 0..31
    int i  = idx & (NHID - 1);
    lds[i * 32 + om] = w2[(size_t)(o0 + om) * NHID + i];
  }
  if (threadIdx.x < 32) lds[NHID * 32 + threadIdx.x] = 0.0f;  // sentinel row
  __syncthreads();

  int wid = threadIdx.x >> 6, lane = threadIdx.x & 63;
  int col = lane & 31;
  int sh  = (lane >> 5) << 4;      // 0 = even entries, 16 = odd entries
  int b = bq * 4 + wid;
  size_t bt = (size_t)b * NT;
  float* op = out + ((size_t)b * NOUT + o0 + col) * NT;

  float cur = 0.f, vol = 0.f;
  uint32_t sm = 0;
  float P[8], Q[8], R[8];
  u32x4 cA[4], cB[4], rA[4], rB[4];
  u32x2 cN, rN;

#define FC2_LOADG(BUF, CA_, CB_) do {                                           \
    u32x4 ca_ = (CA_), cb_ = (CB_);                                             \
    BUF[0] = lds[((ca_[0] >> sh) & 0xffffu) + col];                             \
    BUF[1] = lds[((ca_[1] >> sh) & 0xffffu) + col];                             \
    BUF[2] = lds[((ca_[2] >> sh) & 0xffffu) + col];                             \
    BUF[3] = lds[((ca_[3] >> sh) & 0xffffu) + col];                             \
    BUF[4] = lds[((cb_[0] >> sh) & 0xffffu) + col];                             \
    BUF[5] = lds[((cb_[1] >> sh) & 0xffffu) + col];                             \
    BUF[6] = lds[((cb_[2] >> sh) & 0xffffu) + col];                             \
    BUF[7] = lds[((cb_[3] >> sh) & 0xffffu) + col];                             \
  } while (0)

#define FC2_JOIN(RA, RB, RN)                                                    \
    asm volatile("s_waitcnt vmcnt(0)"                                           \
      : "+v"(RA[0]), "+v"(RA[1]), "+v"(RA[2]), "+v"(RA[3]),                     \
        "+v"(RB[0]), "+v"(RB[1]), "+v"(RB[2]), "+v"(RB[3]), "+v"(RN)            \
      :: "memory")

#define FC2_FLUSH(PV) do {                                                      \
    if (lane < 32) {                                                            \
      float vb[16];                                                             \
      _Pragma("unroll")                                                         \
      for (int q = 0; q < 16; ++q) vb[q] = ((sm >> q) & 1u) ? 1.0f : 0.0f;      \
      float4* dst = (float4*)(op + ((PV) - 15));                                \
      dst[0] = make_float4(vb[0],  vb[1],  vb[2],  vb[3]);                      \
      dst[1] = make_float4(vb[4],  vb[5],  vb[6],  vb[7]);                      \
      dst[2] = make_float4(vb[8],  vb[9],  vb[10], vb[11]);                     \
      dst[3] = make_float4(vb[12], vb[13], vb[14], vb[15]);                     \
    }                                                                           \
  } while (0)

  // Prologue: stream A of body(0) = s1[-1] -> sentinels (ng 0);
  // stream B = L(0) (plain loads).
#pragma unroll
  for (int k = 0; k < 4; ++k)
    cA[k] = (u32x4){0x80008000u, 0x80008000u, 0x80008000u, 0x80008000u};
  {
    const u32x4* Lz = (const u32x4*)(list2 + bt * LSTRIDE);
#pragma unroll
    for (int k = 0; k < 4; ++k) cB[k] = Lz[k];
    cN[0] = 0; cN[1] = cnt2[bt];
  }
  FC2_LOADG(P, cA[0], cA[1]);   // sentinel reads, +0.0f
  FC2_LOADG(Q, cB[0], cB[1]);

#define FC2_BODY(TAU, CA, CB, CN, RA, RB, RN) do {                              \
    const int tau_ = (TAU);                                                     \
    const uint16_t* lp_ = list2 + (bt + tau_ + 1) * LSTRIDE;                    \
    const uint32_t* cp_ = cnt2 + (bt + tau_ + 1);                               \
    GL4(RA[0], lp_, "0");   GL4(RA[1], lp_, "16");                              \
    GL4(RA[2], lp_, "32");  GL4(RA[3], lp_, "48");                              \
    GL4(RB[0], lp_, "256"); GL4(RB[1], lp_, "272");                             \
    GL4(RB[2], lp_, "288"); GL4(RB[3], lp_, "304");                             \
    GL2(RN, cp_);                                                               \
    float accA = 0.f, accB = 0.f;                                               \
    FC2_LOADG(R, CA[2], CA[3]);  SUM8(accA, P);                                 \
    FC2_LOADG(P, CB[2], CB[3]);  SUM8(accB, Q);                                 \
    SUM8(accA, R);  SUM8(accB, P);                                              \
    int ngA_ = __builtin_amdgcn_readfirstlane((int)CN[0]);                      \
    int ngB_ = __builtin_amdgcn_readfirstlane((int)CN[1]);                      \
    int gmx_ = ngA_ > ngB_ ? ngA_ : ngB_;                                       \
    if (__builtin_expect(gmx_ > 2, 0)) {   /* rare: hidden rate is low */       \
      const u32x4* LsA_ = (const u32x4*)(list2 + (bt + tau_) * LSTRIDE) - 16;   \
      const u32x4* LsB_ = LsA_ + 16;                                            \
      for (int g = 2; g < gmx_; ++g) {                                          \
        if (g < ngA_) { u32x4 x0 = LsA_[2*g], x1 = LsA_[2*g+1];                 \
                        FC2_LOADG(R, x0, x1); SUM8(accA, R); }                  \
        if (g < ngB_) { u32x4 x0 = LsB_[2*g], x1 = LsB_[2*g+1];                 \
                        FC2_LOADG(R, x0, x1); SUM8(accB, R); }                  \
      }                                                                         \
    }                                                                           \
    FC2_JOIN(RA, RB, RN);                                                       \
    FC2_LOADG(P, RA[0], RA[1]);                                                 \
    FC2_LOADG(Q, RB[0], RB[1]);                                                 \
    accA += __shfl_xor(accA, 32, 64);   /* even+odd halves, commutative */      \
    cur = A_I * cur + WSC * accA;                                               \
    vol = A_V * vol + cur;                                                      \
    bool sA_ = vol >= THETA;  vol = sA_ ? 0.f : vol;                            \
    int pA_ = tau_ + 1;                                                         \
    if (sA_) sm |= 1u << (pA_ & 15);                                            \
    if ((pA_ & 15) == 15) { FC2_FLUSH(pA_); sm = 0; }                           \
    accB += __shfl_xor(accB, 32, 64);                                           \
    cur = A_I * cur + WSC * accB;                                               \
    vol = A_V * vol + cur;                                                      \
    bool sB_ = vol >= THETA;  vol = sB_ ? 0.f : vol;                            \
    int pB_ = tau_ + 2;                                                         \
    if (sB_) sm |= 1u << (pB_ & 15);                                            \
    /* (pB_ & 15) == 15 impossible: pB_ even, flush points are odd */           \
  } while (0)

  // 511 bodies cover tau = 0..1021; tail handles tau = 1022 (p = 1023).
  for (int tau = 0; tau < 1020; tau += 4) {
    FC2_BODY(tau,     cA, cB, cN, rA, rB, rN);
    FC2_BODY(tau + 2, rA, rB, rN, cA, cB, cN);
  }
  FC2_BODY(1020, cA, cB, cN, rA, rB, rN);
  // Tail: tau = 1022 consumes stream A of the r-generation = L(1021).
  {
    int ng_ = __builtin_amdgcn_readfirstlane((int)rN[0]);
    float accA = 0.f;
    FC2_LOADG(R, rA[2], rA[3]);
    SUM8(accA, P);                 // P preloaded from rA[0], rA[1]
    SUM8(accA, R);
    if (__builtin_expect(ng_ > 2, 0)) {
      const u32x4* Ls_ = (const u32x4*)(list2 + (bt + 1021) * LSTRIDE);
      for (int g = 2; g < ng_; ++g) {
        u32x4 x0 = Ls_[2 * g], x1 = Ls_[2 * g + 1];
        FC2_LOADG(R, x0, x1); SUM8(accA, R);
      }
    }
    accA += __shfl_xor(accA, 32, 64);
    cur = A_I * cur + WSC * accA;
    vol = A_V * vol + cur;
    bool s_ = vol >= THETA;
    if (s_) sm |= 1u << 15;        // p = 1023
    FC2_FLUSH(1023);
  }
#undef FC2_BODY
#undef FC2_LOADG
#undef FC2_JOIN
#undef FC2_FLUSH
}

// ---------------------------------------------------------------------------
// ws layout (bytes): bits1 u32[64K*16] @0 (4MB); cnt1 @4194304 (256KB);
// list1 u16[64K*128] @4456448 (16MB); bits2 u64[64K*16] @21233664 (8MB);
// cnt2 @29622272 (256KB); list2 @29884416 (16MB).
// ---------------------------------------------------------------------------
extern "C" void kernel_launch(void* const* d_in, const int* in_sizes, int n_in,
                              void* d_out, int out_size, void* d_ws, size_t ws_size,
                              hipStream_t stream) {
  const float* x  = (const float*)d_in[0];
  const float* w1 = (const float*)d_in[1];
  const float* w2 = (const float*)d_in[2];
  float* out = (float*)d_out;

  char* ws = (char*)d_ws;
  uint32_t* bits1 = (uint32_t*)(ws);
  uint32_t* cnt1  = (uint32_t*)(ws + 4194304);
  uint16_t* list1 = (uint16_t*)(ws + 4456448);
  uint64_t* bits2 = (uint64_t*)(ws + 21233664);
  uint32_t* cnt2  = (uint32_t*)(ws + 29622272);
  uint16_t* list2 = (uint16_t*)(ws + 29884416);

  const int LDS1 = (513 * 64 + 1024 + 8) * 4;   // tile + state mailbox + flags = 135456
  const int LDS2 = (NHID + 1) * 32 * 4;         // 131200
  (void)hipFuncSetAttribute((const void*)k_fc1,
      hipFuncAttributeMaxDynamicSharedMemorySize, LDS1);
  (void)hipFuncSetAttribute((const void*)k_fc2,
      hipFuncAttributeMaxDynamicSharedMemorySize, LDS2);

  k_bits1 <<<NB * 16 * 4, 256, 0, stream>>>(x, bits1);
  k_extract<<<(NB * NT) / 256, 256, 0, stream>>>((const uint64_t*)bits1, cnt1,
                                                 list1, 8, NIN << 6, 6);
  k_fc1   <<<16 * 16, 512, LDS1, stream>>>(w1, cnt1, list1, bits2);
  k_extract<<<(NB * NT) / 256, 256, 0, stream>>>((const uint64_t*)bits2, cnt2,
                                                 list2, 16, NHID << 5, 5);
  k_fc2   <<<16 * 16, 256, LDS2, stream>>>(w2, cnt2, list2, out);
}

// Round 11
// 841.244 us; speedup vs baseline: 2.4517x; 1.1447x over previous
//
#include <hip/hip_runtime.h>
#include <stdint.h>

// Problem sizes (fixed by reference)
#define NB   64
#define NIN  512
#define NHID 1024
#define NOUT 512
#define NT   1024

#define LSTRIDE 128   // u16 entries per (b,t) list, sentinel-padded to FULL length

// Loihi CUBA constants (exact in fp32)
#define A_I   0.75f
#define A_V   0.96875f
#define WSC   64.0f
#define THETA 5120.0f

typedef uint32_t u32x4 __attribute__((ext_vector_type(4)));
typedef uint32_t u32x2 __attribute__((ext_vector_type(2)));

// Un-sinkable prefetch: real global_load issued HERE (volatile asm). The
// matching s_waitcnt join takes the destination registers as "+v" operands,
// so later uses are data-ordered after the wait; volatile<->volatile order
// keeps the loads at the issue point. JOINS ARE ALWAYS vmcnt(0): stores and
// compiler-emitted loads also tick vmcnt, so counted joins under-wait.
#define GL4(DST, PTR, OFF) \
  asm volatile("global_load_dwordx4 %0, %1, off offset:" OFF : "=v"(DST) : "v"(PTR))
#define GL2(DST, PTR) \
  asm volatile("global_load_dwordx2 %0, %1, off" : "=v"(DST) : "v"(PTR))
#define GL1(DST, PTR) \
  asm volatile("global_load_dword %0, %1, off" : "=v"(DST) : "v"(PTR))

// LDS-only ordering fence (state mailbox). NOT __threadfence_block(): that
// emits vmcnt(0) too and would drain the list prefetch pipeline.
#define LDS_FENCE() asm volatile("s_waitcnt lgkmcnt(0)" ::: "memory")

// ---------------------------------------------------------------------------
// K1: binarize x (B,Nin,T) fp32 -> bitmask bits1[b][t][iw] (u32), coalesced.
// ---------------------------------------------------------------------------
__global__ void __launch_bounds__(256) k_bits1(const float* __restrict__ x,
                                               uint32_t* __restrict__ bits1) {
  int blk = blockIdx.x;          // b*64 + iw*4 + tc
  int b  = blk >> 6;
  int iw = (blk >> 2) & 15;
  int tc = blk & 3;
  int t  = tc * 256 + threadIdx.x;
  const float* xp = x + ((size_t)(b * NIN + iw * 32)) * NT + t;
  uint32_t w = 0;
#pragma unroll
  for (int j = 0; j < 32; ++j) {
    float v = xp[(size_t)j * NT];
    if (v > 0.5f) w |= (1u << j);
  }
  bits1[((size_t)b * NT + t) * 16 + iw] = w;
}

// ---------------------------------------------------------------------------
// Extract per-(b,t) ascending index lists, PRE-SCALED by <<shift (consumer's
// LDS dword index = val + lane/col). cnt stores the GROUP count ceil(c/16).
// Full LSTRIDE sentinel-padded (sentinel maps to the zeroed LDS row; +0.0f
// adds are bit-neutral).
// ---------------------------------------------------------------------------
__global__ void __launch_bounds__(256) k_extract(const uint64_t* __restrict__ bits,
                                                 uint32_t* __restrict__ cnt,
                                                 uint16_t* __restrict__ list,
                                                 int words, int sentinel_scaled,
                                                 int shift) {
  int gid = blockIdx.x * 256 + threadIdx.x;   // = b*NT + t
  const uint64_t* wp = bits + (size_t)gid * words;
  uint16_t* lp = list + (size_t)gid * LSTRIDE;
  int c = 0;
  for (int w = 0; w < words; ++w) {
    uint64_t v = wp[w];
    while (v) {
      int j = __builtin_ctzll(v);
      v &= v - 1;
      if (c < LSTRIDE) lp[c] = (uint16_t)(((w << 6) + j) << shift);
      ++c;
    }
  }
  if (c > LSTRIDE) c = LSTRIDE;
  cnt[gid] = (uint32_t)((c + 15) >> 4);       // group count
  int cp = c;
  if (cp & 1) { lp[cp] = (uint16_t)sentinel_scaled; ++cp; }
  uint32_t s2 = (uint32_t)sentinel_scaled * 0x10001u;
  uint32_t* lp32 = (uint32_t*)lp;
  for (int k = cp >> 1; k < LSTRIDE / 2; ++k) lp32[k] = s2;
}

// Sequential single-accumulator sums: order = ascending list entries,
// bit-identical to the validated round-1/3/4/5/9/10 kernels.
#define SUM16(ACC, B) do { _Pragma("unroll") \
  for (int q_ = 0; q_ < 16; ++q_) (ACC) += (B)[q_]; } while (0)
#define SUM8(ACC, B) do { _Pragma("unroll") \
  for (int q_ = 0; q_ < 8; ++q_) (ACC) += (B)[q_]; } while (0)

// ---------------------------------------------------------------------------
// K2: fused fc1 + LIF -> spike bitmask bits2[b][t][hq] (u64).
// 4-PARITY TIME-PAIRED WAVES: block = 1024 threads = 16 waves = 4 chains x
// 4 parities. Chain c = wave&3 (batch bq*4+c, 64 lanes = 64 hidden cols, the
// validated per-wave geometry); parity = wave>>2 owns t === par (mod 4).
// Per-SIMD work is invariant vs R10 (1024 timesteps) -- 4 resident waves
// now fill each other's ds/branch/join stalls. Serial LIF state (cur,vol)
// hops par -> par+1 via the proven LDS mailbox (write state -> lgkmcnt(0)
// -> flag = t; consumer spins flag[(par+3)&3] >= t-1, fences, reads). No
// __syncthreads in the loop. Lists prefetched per body (t+4) via volatile
// global_load, joined with vmcnt(0). Gather = branchless 4 ascending groups
// (sentinel-exact); rare ng>4 -> guarded L2 slow path. Arithmetic order per
// neuron unchanged.
// ---------------------------------------------------------------------------
__global__ void __launch_bounds__(1024, 4) k_fc1(const float* __restrict__ w1,
                                                 const uint32_t* __restrict__ cnt1,
                                                 const uint16_t* __restrict__ list1,
                                                 uint64_t* __restrict__ bits2) {
  extern __shared__ float lds[];   // tile 513x64 | state [4][4][64]f2 | flags [4][4]
  int xcd = blockIdx.x & 7, slot = blockIdx.x >> 3;
  int bq = (xcd << 1) | (slot & 1);
  int hq = slot >> 1;
  int h0 = hq * 64;
  for (int idx = threadIdx.x; idx < NIN * 64; idx += 1024) {
    int hl = idx >> 9;             // 0..63
    int i  = idx & (NIN - 1);
    lds[i * 64 + hl] = w1[(size_t)(h0 + hl) * NIN + i];
  }
  if (threadIdx.x < 64) lds[NIN * 64 + threadIdx.x] = 0.0f;  // sentinel row
  float* stbase = lds + 32832;               // 2048 dwords of state
  int*   flbase = (int*)(lds + 32832 + 2048);
  stbase[threadIdx.x]        = 0.0f;         // zero all state (2x1024 dwords)
  stbase[1024 + threadIdx.x] = 0.0f;
  if (threadIdx.x < 16)
    flbase[threadIdx.x] = (int)(threadIdx.x >> 2) - 4;  // flag[par][c] = par-4
  __syncthreads();

  int wid = threadIdx.x >> 6, lane = threadIdx.x & 63;
  int c   = wid & 3;               // chain (batch)
  int par = wid >> 2;              // parity: owns t === par (mod 4)
  int b = bq * 4 + c;
  size_t bt = (size_t)b * NT;
  float2* stMine = (float2*)(stbase + (par * 4 + c) * 128);
  float2* stPart = (float2*)(stbase + (((par + 3) & 3) * 4 + c) * 128);
  volatile int* flMine = flbase + par * 4 + c;
  volatile int* flPart = flbase + ((par + 3) & 3) * 4 + c;

  float P[16], Q[16], R[16];
  u32x4 ct[8], rt[8];
  int cntC;
  {
    const u32x4* Lp = (const u32x4*)(list1 + (bt + par) * LSTRIDE);
#pragma unroll
    for (int k = 0; k < 8; ++k) ct[k] = Lp[k];
    cntC = (int)cnt1[bt + par];
  }

#define FC1_LOADG(BUF, CA_, CB_) do {                                           \
    u32x4 ca_ = (CA_), cb_ = (CB_);                                             \
    BUF[0]  = lds[(ca_[0] & 0xffffu) + lane];                                   \
    BUF[1]  = lds[(ca_[0] >> 16)     + lane];                                   \
    BUF[2]  = lds[(ca_[1] & 0xffffu) + lane];                                   \
    BUF[3]  = lds[(ca_[1] >> 16)     + lane];                                   \
    BUF[4]  = lds[(ca_[2] & 0xffffu) + lane];                                   \
    BUF[5]  = lds[(ca_[2] >> 16)     + lane];                                   \
    BUF[6]  = lds[(ca_[3] & 0xffffu) + lane];                                   \
    BUF[7]  = lds[(ca_[3] >> 16)     + lane];                                   \
    BUF[8]  = lds[(cb_[0] & 0xffffu) + lane];                                   \
    BUF[9]  = lds[(cb_[0] >> 16)     + lane];                                   \
    BUF[10] = lds[(cb_[1] & 0xffffu) + lane];                                   \
    BUF[11] = lds[(cb_[1] >> 16)     + lane];                                   \
    BUF[12] = lds[(cb_[2] & 0xffffu) + lane];                                   \
    BUF[13] = lds[(cb_[2] >> 16)     + lane];                                   \
    BUF[14] = lds[(cb_[3] & 0xffffu) + lane];                                   \
    BUF[15] = lds[(cb_[3] >> 16)     + lane];                                   \
  } while (0)

#define FC1_JOIN(RT, CW)                                                        \
    asm volatile("s_waitcnt vmcnt(0)"                                           \
      : "+v"(RT[0]), "+v"(RT[1]), "+v"(RT[2]), "+v"(RT[3]),                     \
        "+v"(RT[4]), "+v"(RT[5]), "+v"(RT[6]), "+v"(RT[7]), "+v"(CW)            \
      :: "memory")

#define FC1_BODY(T, CT, RT) do {                                                \
    const int t_ = (T);                                                         \
    int tp_ = t_ + 4;  if (tp_ > NT - 1) tp_ = NT - 1;                          \
    const uint16_t* lp_ = list1 + (bt + tp_) * LSTRIDE;                         \
    const uint32_t* cp_ = cnt1 + (bt + tp_);                                    \
    uint32_t cw_;                                                               \
    GL1(cw_, cp_);                                                              \
    GL4(RT[0], lp_, "0");   GL4(RT[1], lp_, "16");                              \
    GL4(RT[2], lp_, "32");  GL4(RT[3], lp_, "48");                              \
    GL4(RT[4], lp_, "64");  GL4(RT[5], lp_, "80");                              \
    GL4(RT[6], lp_, "96");  GL4(RT[7], lp_, "112");                             \
    int ng_ = __builtin_amdgcn_readfirstlane(cntC);                             \
    float acc = 0.f;                                                            \
    /* branchless 4 groups, 3-buffer rotation (sentinel-exact, ascending) */    \
    FC1_LOADG(P, CT[0], CT[1]);                                                 \
    FC1_LOADG(Q, CT[2], CT[3]);                                                 \
    SUM16(acc, P);                                                              \
    FC1_LOADG(R, CT[4], CT[5]);                                                 \
    SUM16(acc, Q);                                                              \
    FC1_LOADG(P, CT[6], CT[7]);                                                 \
    SUM16(acc, R);                                                              \
    SUM16(acc, P);                                                              \
    if (__builtin_expect(ng_ > 4, 0)) {   /* ~2.4% of timesteps */              \
      const u32x4* Lc_ = (const u32x4*)(list1 + (bt + t_) * LSTRIDE);           \
      for (int g = 4; g < ng_; ++g) {                                           \
        u32x4 x0 = Lc_[2 * g], x1 = Lc_[2 * g + 1];                             \
        FC1_LOADG(R, x0, x1);                                                   \
        SUM16(acc, R);                                                          \
      }                                                                         \
    }                                                                           \
    FC1_JOIN(RT, cw_);                                                          \
    /* LIF: state arrives from parity (par+3)&3 (owns t-1), result goes on */   \
    {                                                                           \
      int want_ = t_ - 1;                                                       \
      for (;;) {                                                                \
        int fl_ = *flPart;                                                      \
        if (fl_ >= want_) break;                                                \
        __builtin_amdgcn_s_sleep(1);                                            \
      }                                                                         \
      LDS_FENCE();                                                              \
      float2 sv_ = stPart[lane];                                                \
      float cur_ = A_I * sv_.x + WSC * acc;                                     \
      float vol_ = A_V * sv_.y + cur_;                                          \
      bool s_ = vol_ >= THETA;                                                  \
      vol_ = s_ ? 0.f : vol_;                                                   \
      stMine[lane] = make_float2(cur_, vol_);                                   \
      LDS_FENCE();                                                              \
      if (lane == 0) *flMine = t_;                                              \
      unsigned long long m_ = __ballot(s_);                                     \
      if (lane == 0) bits2[(bt + t_) * 16 + hq] = m_;                           \
    }                                                                           \
    cntC = (int)cw_;                                                            \
  } while (0)

  // 256 bodies per wave: t = par, par+4, ..., par+1020 (all 1024 t covered
  // across the 4 parities).
  for (int k = 0; k < 128; ++k) {
    FC1_BODY(par + 8 * k,     ct, rt);
    FC1_BODY(par + 8 * k + 4, rt, ct);
  }
#undef FC1_BODY
#undef FC1_LOADG
#undef FC1_JOIN
}

// ---------------------------------------------------------------------------
// K3: fused fc2 + LIF + both delay shifts -> final fp32 spikes.
// VERBATIM validated R9/R10 kernel. 4 waves = 4 batches; lanes 0..31 / 32..63
// take even/odd list entries for the same 32 outputs, combined via one
// commutative shfl_xor(32) add. TWO timesteps per body, P/Q/R rotation,
// one 9-load prefetch joined per body with vmcnt(0). Input at tau is
// s1[tau-1]; out[p] = spike2[p-1]; 16-p register-buffered 64 B stores.
// ---------------------------------------------------------------------------
__global__ void __launch_bounds__(256, 1) k_fc2(const float* __restrict__ w2,
                                                const uint32_t* __restrict__ cnt2,
                                                const uint16_t* __restrict__ list2,
                                                float* __restrict__ out) {
  extern __shared__ float lds[];   // (NHID+1) x 32
  int xcd = blockIdx.x & 7, slot = blockIdx.x >> 3;
  int bq = (xcd << 1) | (slot & 1);
  int oq = slot >> 1;
  int o0 = oq * 32;
  for (int idx = threadIdx.x; idx < NHID * 32; idx += 256) {
    int om = idx >> 10;            // 0..31
    int i  = idx & (NHID - 1);
    lds[i * 32 + om] = w2[(size_t)(o0 + om) * NHID + i];
  }
  if (threadIdx.x < 32) lds[NHID * 32 + threadIdx.x] = 0.0f;  // sentinel row
  __syncthreads();

  int wid = threadIdx.x >> 6, lane = threadIdx.x & 63;
  int col = lane & 31;
  int sh  = (lane >> 5) << 4;      // 0 = even entries, 16 = odd entries
  int b = bq * 4 + wid;
  size_t bt = (size_t)b * NT;
  float* op = out + ((size_t)b * NOUT + o0 + col) * NT;

  float cur = 0.f, vol = 0.f;
  uint32_t sm = 0;
  float P[8], Q[8], R[8];
  u32x4 cA[4], cB[4], rA[4], rB[4];
  u32x2 cN, rN;

#define FC2_LOADG(BUF, CA_, CB_) do {                                           \
    u32x4 ca_ = (CA_), cb_ = (CB_);                                             \
    BUF[0] = lds[((ca_[0] >> sh) & 0xffffu) + col];                             \
    BUF[1] = lds[((ca_[1] >> sh) & 0xffffu) + col];                             \
    BUF[2] = lds[((ca_[2] >> sh) & 0xffffu) + col];                             \
    BUF[3] = lds[((ca_[3] >> sh) & 0xffffu) + col];                             \
    BUF[4] = lds[((cb_[0] >> sh) & 0xffffu) + col];                             \
    BUF[5] = lds[((cb_[1] >> sh) & 0xffffu) + col];                             \
    BUF[6] = lds[((cb_[2] >> sh) & 0xffffu) + col];                             \
    BUF[7] = lds[((cb_[3] >> sh) & 0xffffu) + col];                             \
  } while (0)

#define FC2_JOIN(RA, RB, RN)                                                    \
    asm volatile("s_waitcnt vmcnt(0)"                                           \
      : "+v"(RA[0]), "+v"(RA[1]), "+v"(RA[2]), "+v"(RA[3]),                     \
        "+v"(RB[0]), "+v"(RB[1]), "+v"(RB[2]), "+v"(RB[3]), "+v"(RN)            \
      :: "memory")

#define FC2_FLUSH(PV) do {                                                      \
    if (lane < 32) {                                                            \
      float vb[16];                                                             \
      _Pragma("unroll")                                                         \
      for (int q = 0; q < 16; ++q) vb[q] = ((sm >> q) & 1u) ? 1.0f : 0.0f;      \
      float4* dst = (float4*)(op + ((PV) - 15));                                \
      dst[0] = make_float4(vb[0],  vb[1],  vb[2],  vb[3]);                      \
      dst[1] = make_float4(vb[4],  vb[5],  vb[6],  vb[7]);                      \
      dst[2] = make_float4(vb[8],  vb[9],  vb[10], vb[11]);                     \
      dst[3] = make_float4(vb[12], vb[13], vb[14], vb[15]);                     \
    }                                                                           \
  } while (0)

  // Prologue: stream A of body(0) = s1[-1] -> sentinels (ng 0);
  // stream B = L(0) (plain loads).
#pragma unroll
  for (int k = 0; k < 4; ++k)
    cA[k] = (u32x4){0x80008000u, 0x80008000u, 0x80008000u, 0x80008000u};
  {
    const u32x4* Lz = (const u32x4*)(list2 + bt * LSTRIDE);
#pragma unroll
    for (int k = 0; k < 4; ++k) cB[k] = Lz[k];
    cN[0] = 0; cN[1] = cnt2[bt];
  }
  FC2_LOADG(P, cA[0], cA[1]);   // sentinel reads, +0.0f
  FC2_LOADG(Q, cB[0], cB[1]);

#define FC2_BODY(TAU, CA, CB, CN, RA, RB, RN) do {                              \
    const int tau_ = (TAU);                                                     \
    const uint16_t* lp_ = list2 + (bt + tau_ + 1) * LSTRIDE;                    \
    const uint32_t* cp_ = cnt2 + (bt + tau_ + 1);                               \
    GL4(RA[0], lp_, "0");   GL4(RA[1], lp_, "16");                              \
    GL4(RA[2], lp_, "32");  GL4(RA[3], lp_, "48");                              \
    GL4(RB[0], lp_, "256"); GL4(RB[1], lp_, "272");                             \
    GL4(RB[2], lp_, "288"); GL4(RB[3], lp_, "304");                             \
    GL2(RN, cp_);                                                               \
    float accA = 0.f, accB = 0.f;                                               \
    FC2_LOADG(R, CA[2], CA[3]);  SUM8(accA, P);                                 \
    FC2_LOADG(P, CB[2], CB[3]);  SUM8(accB, Q);                                 \
    SUM8(accA, R);  SUM8(accB, P);                                              \
    int ngA_ = __builtin_amdgcn_readfirstlane((int)CN[0]);                      \
    int ngB_ = __builtin_amdgcn_readfirstlane((int)CN[1]);                      \
    int gmx_ = ngA_ > ngB_ ? ngA_ : ngB_;                                       \
    if (__builtin_expect(gmx_ > 2, 0)) {   /* rare: hidden rate is low */       \
      const u32x4* LsA_ = (const u32x4*)(list2 + (bt + tau_) * LSTRIDE) - 16;   \
      const u32x4* LsB_ = LsA_ + 16;                                            \
      for (int g = 2; g < gmx_; ++g) {                                          \
        if (g < ngA_) { u32x4 x0 = LsA_[2*g], x1 = LsA_[2*g+1];                 \
                        FC2_LOADG(R, x0, x1); SUM8(accA, R); }                  \
        if (g < ngB_) { u32x4 x0 = LsB_[2*g], x1 = LsB_[2*g+1];                 \
                        FC2_LOADG(R, x0, x1); SUM8(accB, R); }                  \
      }                                                                         \
    }                                                                           \
    FC2_JOIN(RA, RB, RN);                                                       \
    FC2_LOADG(P, RA[0], RA[1]);                                                 \
    FC2_LOADG(Q, RB[0], RB[1]);                                                 \
    accA += __shfl_xor(accA, 32, 64);   /* even+odd halves, commutative */      \
    cur = A_I * cur + WSC * accA;                                               \
    vol = A_V * vol + cur;                                                      \
    bool sA_ = vol >= THETA;  vol = sA_ ? 0.f : vol;                            \
    int pA_ = tau_ + 1;                                                         \
    if (sA_) sm |= 1u << (pA_ & 15);                                            \
    if ((pA_ & 15) == 15) { FC2_FLUSH(pA_); sm = 0; }                           \
    accB += __shfl_xor(accB, 32, 64);                                           \
    cur = A_I * cur + WSC * accB;                                               \
    vol = A_V * vol + cur;                                                      \
    bool sB_ = vol >= THETA;  vol = sB_ ? 0.f : vol;                            \
    int pB_ = tau_ + 2;                                                         \
    if (sB_) sm |= 1u << (pB_ & 15);                                            \
    /* (pB_ & 15) == 15 impossible: pB_ even, flush points are odd */           \
  } while (0)

  // 511 bodies cover tau = 0..1021; tail handles tau = 1022 (p = 1023).
  for (int tau = 0; tau < 1020; tau += 4) {
    FC2_BODY(tau,     cA, cB, cN, rA, rB, rN);
    FC2_BODY(tau + 2, rA, rB, rN, cA, cB, cN);
  }
  FC2_BODY(1020, cA, cB, cN, rA, rB, rN);
  // Tail: tau = 1022 consumes stream A of the r-generation = L(1021).
  {
    int ng_ = __builtin_amdgcn_readfirstlane((int)rN[0]);
    float accA = 0.f;
    FC2_LOADG(R, rA[2], rA[3]);
    SUM8(accA, P);                 // P preloaded from rA[0], rA[1]
    SUM8(accA, R);
    if (__builtin_expect(ng_ > 2, 0)) {
      const u32x4* Ls_ = (const u32x4*)(list2 + (bt + 1021) * LSTRIDE);
      for (int g = 2; g < ng_; ++g) {
        u32x4 x0 = Ls_[2 * g], x1 = Ls_[2 * g + 1];
        FC2_LOADG(R, x0, x1); SUM8(accA, R);
      }
    }
    accA += __shfl_xor(accA, 32, 64);
    cur = A_I * cur + WSC * accA;
    vol = A_V * vol + cur;
    bool s_ = vol >= THETA;
    if (s_) sm |= 1u << 15;        // p = 1023
    FC2_FLUSH(1023);
  }
#undef FC2_BODY
#undef FC2_LOADG
#undef FC2_JOIN
#undef FC2_FLUSH
}

// ---------------------------------------------------------------------------
// ws layout (bytes): bits1 u32[64K*16] @0 (4MB); cnt1 @4194304 (256KB);
// list1 u16[64K*128] @4456448 (16MB); bits2 u64[64K*16] @21233664 (8MB);
// cnt2 @29622272 (256KB); list2 @29884416 (16MB).
// ---------------------------------------------------------------------------
extern "C" void kernel_launch(void* const* d_in, const int* in_sizes, int n_in,
                              void* d_out, int out_size, void* d_ws, size_t ws_size,
                              hipStream_t stream) {
  const float* x  = (const float*)d_in[0];
  const float* w1 = (const float*)d_in[1];
  const float* w2 = (const float*)d_in[2];
  float* out = (float*)d_out;

  char* ws = (char*)d_ws;
  uint32_t* bits1 = (uint32_t*)(ws);
  uint32_t* cnt1  = (uint32_t*)(ws + 4194304);
  uint16_t* list1 = (uint16_t*)(ws + 4456448);
  uint64_t* bits2 = (uint64_t*)(ws + 21233664);
  uint32_t* cnt2  = (uint32_t*)(ws + 29622272);
  uint16_t* list2 = (uint16_t*)(ws + 29884416);

  const int LDS1 = (513 * 64 + 2048 + 16) * 4;  // tile + 4-par mailbox + flags = 139584
  const int LDS2 = (NHID + 1) * 32 * 4;         // 131200
  (void)hipFuncSetAttribute((const void*)k_fc1,
      hipFuncAttributeMaxDynamicSharedMemorySize, LDS1);
  (void)hipFuncSetAttribute((const void*)k_fc2,
      hipFuncAttributeMaxDynamicSharedMemorySize, LDS2);

  k_bits1 <<<NB * 16 * 4, 256, 0, stream>>>(x, bits1);
  k_extract<<<(NB * NT) / 256, 256, 0, stream>>>((const uint64_t*)bits1, cnt1,
                                                 list1, 8, NIN << 6, 6);
  k_fc1   <<<16 * 16, 1024, LDS1, stream>>>(w1, cnt1, list1, bits2);
  k_extract<<<(NB * NT) / 256, 256, 0, stream>>>((const uint64_t*)bits2, cnt2,
                                                 list2, 16, NHID << 5, 5);
  k_fc2   <<<16 * 16, 256, LDS2, stream>>>(w2, cnt2, list2, out);
}

// Round 12
// 769.773 us; speedup vs baseline: 2.6793x; 1.0928x over previous
//
#include <hip/hip_runtime.h>
#include <stdint.h>

// Problem sizes (fixed by reference)
#define NB   64
#define NIN  512
#define NHID 1024
#define NOUT 512
#define NT   1024

#define LSTRIDE 128   // u16 entries per (b,t) list, sentinel-padded to FULL length

// Loihi CUBA constants (exact in fp32)
#define A_I   0.75f
#define A_V   0.96875f
#define WSC   64.0f
#define THETA 5120.0f

typedef uint32_t u32x4 __attribute__((ext_vector_type(4)));
typedef uint32_t u32x2 __attribute__((ext_vector_type(2)));

// Un-sinkable prefetch: real global_load issued HERE (volatile asm). The
// matching s_waitcnt join takes the destination registers as "+v" operands,
// so later uses are data-ordered after the wait; volatile<->volatile order
// keeps the loads at the issue point. JOINS ARE ALWAYS vmcnt(0): stores and
// compiler-emitted loads also tick vmcnt, so counted joins under-wait.
#define GL4(DST, PTR, OFF) \
  asm volatile("global_load_dwordx4 %0, %1, off offset:" OFF : "=v"(DST) : "v"(PTR))
#define GL1(DST, PTR) \
  asm volatile("global_load_dword %0, %1, off" : "=v"(DST) : "v"(PTR))

// LDS-only ordering fence (state mailbox). NOT __threadfence_block(): that
// emits vmcnt(0) too and would drain the list prefetch pipeline.
#define LDS_FENCE() asm volatile("s_waitcnt lgkmcnt(0)" ::: "memory")

// ---------------------------------------------------------------------------
// K1: binarize x (B,Nin,T) fp32 -> bitmask bits1[b][t][iw] (u32), coalesced.
// ---------------------------------------------------------------------------
__global__ void __launch_bounds__(256) k_bits1(const float* __restrict__ x,
                                               uint32_t* __restrict__ bits1) {
  int blk = blockIdx.x;          // b*64 + iw*4 + tc
  int b  = blk >> 6;
  int iw = (blk >> 2) & 15;
  int tc = blk & 3;
  int t  = tc * 256 + threadIdx.x;
  const float* xp = x + ((size_t)(b * NIN + iw * 32)) * NT + t;
  uint32_t w = 0;
#pragma unroll
  for (int j = 0; j < 32; ++j) {
    float v = xp[(size_t)j * NT];
    if (v > 0.5f) w |= (1u << j);
  }
  bits1[((size_t)b * NT + t) * 16 + iw] = w;
}

// ---------------------------------------------------------------------------
// Extract per-(b,t) ascending index lists, PRE-SCALED by <<shift (consumer's
// LDS dword index = val + lane/col). cnt stores the GROUP count ceil(c/16).
// Full LSTRIDE sentinel-padded (sentinel maps to the zeroed LDS row; +0.0f
// adds are bit-neutral).
// ---------------------------------------------------------------------------
__global__ void __launch_bounds__(256) k_extract(const uint64_t* __restrict__ bits,
                                                 uint32_t* __restrict__ cnt,
                                                 uint16_t* __restrict__ list,
                                                 int words, int sentinel_scaled,
                                                 int shift) {
  int gid = blockIdx.x * 256 + threadIdx.x;   // = b*NT + t
  const uint64_t* wp = bits + (size_t)gid * words;
  uint16_t* lp = list + (size_t)gid * LSTRIDE;
  int c = 0;
  for (int w = 0; w < words; ++w) {
    uint64_t v = wp[w];
    while (v) {
      int j = __builtin_ctzll(v);
      v &= v - 1;
      if (c < LSTRIDE) lp[c] = (uint16_t)(((w << 6) + j) << shift);
      ++c;
    }
  }
  if (c > LSTRIDE) c = LSTRIDE;
  cnt[gid] = (uint32_t)((c + 15) >> 4);       // group count
  int cp = c;
  if (cp & 1) { lp[cp] = (uint16_t)sentinel_scaled; ++cp; }
  uint32_t s2 = (uint32_t)sentinel_scaled * 0x10001u;
  uint32_t* lp32 = (uint32_t*)lp;
  for (int k = cp >> 1; k < LSTRIDE / 2; ++k) lp32[k] = s2;
}

// Sequential single-accumulator sums: order = ascending list entries,
// bit-identical to the validated round-1/3/4/5/9/10/11 kernels.
#define SUM16(ACC, B) do { _Pragma("unroll") \
  for (int q_ = 0; q_ < 16; ++q_) (ACC) += (B)[q_]; } while (0)
#define SUM8(ACC, B) do { _Pragma("unroll") \
  for (int q_ = 0; q_ < 8; ++q_) (ACC) += (B)[q_]; } while (0)

// ---------------------------------------------------------------------------
// K2: fused fc1 + LIF -> spike bitmask bits2[b][t][hq] (u64).
// VERBATIM validated R11 kernel (4-parity time-paired waves, LDS mailbox).
// ---------------------------------------------------------------------------
__global__ void __launch_bounds__(1024, 4) k_fc1(const float* __restrict__ w1,
                                                 const uint32_t* __restrict__ cnt1,
                                                 const uint16_t* __restrict__ list1,
                                                 uint64_t* __restrict__ bits2) {
  extern __shared__ float lds[];   // tile 513x64 | state [4][4][64]f2 | flags [4][4]
  int xcd = blockIdx.x & 7, slot = blockIdx.x >> 3;
  int bq = (xcd << 1) | (slot & 1);
  int hq = slot >> 1;
  int h0 = hq * 64;
  for (int idx = threadIdx.x; idx < NIN * 64; idx += 1024) {
    int hl = idx >> 9;             // 0..63
    int i  = idx & (NIN - 1);
    lds[i * 64 + hl] = w1[(size_t)(h0 + hl) * NIN + i];
  }
  if (threadIdx.x < 64) lds[NIN * 64 + threadIdx.x] = 0.0f;  // sentinel row
  float* stbase = lds + 32832;               // 2048 dwords of state
  int*   flbase = (int*)(lds + 32832 + 2048);
  stbase[threadIdx.x]        = 0.0f;         // zero all state (2x1024 dwords)
  stbase[1024 + threadIdx.x] = 0.0f;
  if (threadIdx.x < 16)
    flbase[threadIdx.x] = (int)(threadIdx.x >> 2) - 4;  // flag[par][c] = par-4
  __syncthreads();

  int wid = threadIdx.x >> 6, lane = threadIdx.x & 63;
  int c   = wid & 3;               // chain (batch)
  int par = wid >> 2;              // parity: owns t === par (mod 4)
  int b = bq * 4 + c;
  size_t bt = (size_t)b * NT;
  float2* stMine = (float2*)(stbase + (par * 4 + c) * 128);
  float2* stPart = (float2*)(stbase + (((par + 3) & 3) * 4 + c) * 128);
  volatile int* flMine = flbase + par * 4 + c;
  volatile int* flPart = flbase + ((par + 3) & 3) * 4 + c;

  float P[16], Q[16], R[16];
  u32x4 ct[8], rt[8];
  int cntC;
  {
    const u32x4* Lp = (const u32x4*)(list1 + (bt + par) * LSTRIDE);
#pragma unroll
    for (int k = 0; k < 8; ++k) ct[k] = Lp[k];
    cntC = (int)cnt1[bt + par];
  }

#define FC1_LOADG(BUF, CA_, CB_) do {                                           \
    u32x4 ca_ = (CA_), cb_ = (CB_);                                             \
    BUF[0]  = lds[(ca_[0] & 0xffffu) + lane];                                   \
    BUF[1]  = lds[(ca_[0] >> 16)     + lane];                                   \
    BUF[2]  = lds[(ca_[1] & 0xffffu) + lane];                                   \
    BUF[3]  = lds[(ca_[1] >> 16)     + lane];                                   \
    BUF[4]  = lds[(ca_[2] & 0xffffu) + lane];                                   \
    BUF[5]  = lds[(ca_[2] >> 16)     + lane];                                   \
    BUF[6]  = lds[(ca_[3] & 0xffffu) + lane];                                   \
    BUF[7]  = lds[(ca_[3] >> 16)     + lane];                                   \
    BUF[8]  = lds[(cb_[0] & 0xffffu) + lane];                                   \
    BUF[9]  = lds[(cb_[0] >> 16)     + lane];                                   \
    BUF[10] = lds[(cb_[1] & 0xffffu) + lane];                                   \
    BUF[11] = lds[(cb_[1] >> 16)     + lane];                                   \
    BUF[12] = lds[(cb_[2] & 0xffffu) + lane];                                   \
    BUF[13] = lds[(cb_[2] >> 16)     + lane];                                   \
    BUF[14] = lds[(cb_[3] & 0xffffu) + lane];                                   \
    BUF[15] = lds[(cb_[3] >> 16)     + lane];                                   \
  } while (0)

#define FC1_JOIN(RT, CW)                                                        \
    asm volatile("s_waitcnt vmcnt(0)"                                           \
      : "+v"(RT[0]), "+v"(RT[1]), "+v"(RT[2]), "+v"(RT[3]),                     \
        "+v"(RT[4]), "+v"(RT[5]), "+v"(RT[6]), "+v"(RT[7]), "+v"(CW)            \
      :: "memory")

#define FC1_BODY(T, CT, RT) do {                                                \
    const int t_ = (T);                                                         \
    int tp_ = t_ + 4;  if (tp_ > NT - 1) tp_ = NT - 1;                          \
    const uint16_t* lp_ = list1 + (bt + tp_) * LSTRIDE;                         \
    const uint32_t* cp_ = cnt1 + (bt + tp_);                                    \
    uint32_t cw_;                                                               \
    GL1(cw_, cp_);                                                              \
    GL4(RT[0], lp_, "0");   GL4(RT[1], lp_, "16");                              \
    GL4(RT[2], lp_, "32");  GL4(RT[3], lp_, "48");                              \
    GL4(RT[4], lp_, "64");  GL4(RT[5], lp_, "80");                              \
    GL4(RT[6], lp_, "96");  GL4(RT[7], lp_, "112");                             \
    int ng_ = __builtin_amdgcn_readfirstlane(cntC);                             \
    float acc = 0.f;                                                            \
    /* branchless 4 groups, 3-buffer rotation (sentinel-exact, ascending) */    \
    FC1_LOADG(P, CT[0], CT[1]);                                                 \
    FC1_LOADG(Q, CT[2], CT[3]);                                                 \
    SUM16(acc, P);                                                              \
    FC1_LOADG(R, CT[4], CT[5]);                                                 \
    SUM16(acc, Q);                                                              \
    FC1_LOADG(P, CT[6], CT[7]);                                                 \
    SUM16(acc, R);                                                              \
    SUM16(acc, P);                                                              \
    if (__builtin_expect(ng_ > 4, 0)) {   /* ~2.4% of timesteps */              \
      const u32x4* Lc_ = (const u32x4*)(list1 + (bt + t_) * LSTRIDE);           \
      for (int g = 4; g < ng_; ++g) {                                           \
        u32x4 x0 = Lc_[2 * g], x1 = Lc_[2 * g + 1];                             \
        FC1_LOADG(R, x0, x1);                                                   \
        SUM16(acc, R);                                                          \
      }                                                                         \
    }                                                                           \
    FC1_JOIN(RT, cw_);                                                          \
    /* LIF: state arrives from parity (par+3)&3 (owns t-1), result goes on */   \
    {                                                                           \
      int want_ = t_ - 1;                                                       \
      for (;;) {                                                                \
        int fl_ = *flPart;                                                      \
        if (fl_ >= want_) break;                                                \
        __builtin_amdgcn_s_sleep(1);                                            \
      }                                                                         \
      LDS_FENCE();                                                              \
      float2 sv_ = stPart[lane];                                                \
      float cur_ = A_I * sv_.x + WSC * acc;                                     \
      float vol_ = A_V * sv_.y + cur_;                                          \
      bool s_ = vol_ >= THETA;                                                  \
      vol_ = s_ ? 0.f : vol_;                                                   \
      stMine[lane] = make_float2(cur_, vol_);                                   \
      LDS_FENCE();                                                              \
      if (lane == 0) *flMine = t_;                                              \
      unsigned long long m_ = __ballot(s_);                                     \
      if (lane == 0) bits2[(bt + t_) * 16 + hq] = m_;                           \
    }                                                                           \
    cntC = (int)cw_;                                                            \
  } while (0)

  for (int k = 0; k < 128; ++k) {
    FC1_BODY(par + 8 * k,     ct, rt);
    FC1_BODY(par + 8 * k + 4, rt, ct);
  }
#undef FC1_BODY
#undef FC1_LOADG
#undef FC1_JOIN
}

// ---------------------------------------------------------------------------
// K3: fused fc2 + LIF + both delay shifts -> final fp32 spikes.
// 4-PARITY port of the validated R9 fc2 body (per-tau arithmetic byte-
// identical: even/odd lane halves of the same 32 outputs, ascending 2-group
// branchless sum + rare slow path, one commutative shfl_xor(32) combine).
// Block = 1024 threads = 16 waves = 4 chains x 4 parities; wave par owns
// taus === par (mod 4); (cur,vol) hops par->par+1 via the R10/R11-proven
// LDS mailbox. Output: p = tau+1; wave par owns window positions
// {par+1,par+5,par+9,par+13} (mod 16). Each wave posts its 4-bit word to
// LDS at its LAST window position (before its flag, same fence); wave par=2
// (owns pos 15) ORs the 4 words and does the 64 B store. Visibility is
// transitive through the mailbox chain. par3's final body (t=1023, p=1024)
// is a benign dummy (in-bounds reads, un-flushed window-64 bit, unused flag).
// ---------------------------------------------------------------------------
__global__ void __launch_bounds__(1024, 4) k_fc2(const float* __restrict__ w2,
                                                 const uint32_t* __restrict__ cnt2,
                                                 const uint16_t* __restrict__ list2,
                                                 float* __restrict__ out) {
  extern __shared__ float lds[];   // tile 1025x32 | state | flags | sm words
  int xcd = blockIdx.x & 7, slot = blockIdx.x >> 3;
  int bq = (xcd << 1) | (slot & 1);
  int oq = slot >> 1;
  int o0 = oq * 32;
  for (int idx = threadIdx.x; idx < NHID * 32; idx += 1024) {
    int om = idx >> 10;            // 0..31
    int i  = idx & (NHID - 1);
    lds[i * 32 + om] = w2[(size_t)(o0 + om) * NHID + i];
  }
  if (threadIdx.x < 32) lds[NHID * 32 + threadIdx.x] = 0.0f;  // sentinel row
  float*    stbase = lds + 32800;                 // 2048 dwords state
  int*      flbase = (int*)(lds + 32800 + 2048);  // 16 flags
  uint32_t* smwbase = (uint32_t*)(lds + 32800 + 2048 + 16);  // 512 sm words
  stbase[threadIdx.x]        = 0.0f;
  stbase[1024 + threadIdx.x] = 0.0f;
  if (threadIdx.x < 16)
    flbase[threadIdx.x] = (int)(threadIdx.x >> 2) - 4;  // flag[par][c] = par-4
  if (threadIdx.x < 512) smwbase[threadIdx.x] = 0u;
  __syncthreads();

  int wid = threadIdx.x >> 6, lane = threadIdx.x & 63;
  int c   = wid & 3;               // chain (batch)
  int par = wid >> 2;              // parity: owns tau === par (mod 4)
  int col = lane & 31;
  int sh  = (lane >> 5) << 4;      // 0 = even entries, 16 = odd entries
  int b = bq * 4 + c;
  size_t bt = (size_t)b * NT;
  float* op = out + ((size_t)b * NOUT + o0 + col) * NT;
  int lastpos = (par == 3) ? 12 : par + 13;

  float2* stMine = (float2*)(stbase + (par * 4 + c) * 128);
  float2* stPart = (float2*)(stbase + (((par + 3) & 3) * 4 + c) * 128);
  volatile int* flMine = flbase + par * 4 + c;
  volatile int* flPart = flbase + ((par + 3) & 3) * 4 + c;
  uint32_t* smwMine = smwbase + (par * 4 + c) * 32;
  const uint32_t* smw0 = smwbase + (0 * 4 + c) * 32;
  const uint32_t* smw1 = smwbase + (1 * 4 + c) * 32;
  const uint32_t* smw3 = smwbase + (3 * 4 + c) * 32;

  uint32_t sm = 0;
  float P[8], R[8];
  u32x4 ct[4], rt[4];
  int cntC;
  if (par == 0) {                  // body(0) consumes s1[-1] = zeros
#pragma unroll
    for (int k = 0; k < 4; ++k)
      ct[k] = (u32x4){0x80008000u, 0x80008000u, 0x80008000u, 0x80008000u};
    cntC = 0;
  } else {                         // body(par) consumes L(par-1)
    const u32x4* Lz = (const u32x4*)(list2 + (bt + par - 1) * LSTRIDE);
#pragma unroll
    for (int k = 0; k < 4; ++k) ct[k] = Lz[k];
    cntC = (int)cnt2[bt + par - 1];
  }

#define FC2_LOADG(BUF, CA_, CB_) do {                                           \
    u32x4 ca_ = (CA_), cb_ = (CB_);                                             \
    BUF[0] = lds[((ca_[0] >> sh) & 0xffffu) + col];                             \
    BUF[1] = lds[((ca_[1] >> sh) & 0xffffu) + col];                             \
    BUF[2] = lds[((ca_[2] >> sh) & 0xffffu) + col];                             \
    BUF[3] = lds[((ca_[3] >> sh) & 0xffffu) + col];                             \
    BUF[4] = lds[((cb_[0] >> sh) & 0xffffu) + col];                             \
    BUF[5] = lds[((cb_[1] >> sh) & 0xffffu) + col];                             \
    BUF[6] = lds[((cb_[2] >> sh) & 0xffffu) + col];                             \
    BUF[7] = lds[((cb_[3] >> sh) & 0xffffu) + col];                             \
  } while (0)

#define FC2_JOIN(RT, CW)                                                        \
    asm volatile("s_waitcnt vmcnt(0)"                                           \
      : "+v"(RT[0]), "+v"(RT[1]), "+v"(RT[2]), "+v"(RT[3]), "+v"(CW)            \
      :: "memory")

  FC2_LOADG(P, ct[0], ct[1]);      // entries 0..15 of body(par)'s list

#define FC2_BODY(T, CT, RT) do {                                                \
    const int t_ = (T);                                                         \
    int tp_ = t_ + 3;  if (tp_ > NT - 1) tp_ = NT - 1;                          \
    const uint16_t* lp_ = list2 + (bt + tp_) * LSTRIDE;                         \
    const uint32_t* cp_ = cnt2 + (bt + tp_);                                    \
    uint32_t cw_;                                                               \
    GL1(cw_, cp_);                                                              \
    GL4(RT[0], lp_, "0");  GL4(RT[1], lp_, "16");                               \
    GL4(RT[2], lp_, "32"); GL4(RT[3], lp_, "48");                               \
    int ng_ = __builtin_amdgcn_readfirstlane(cntC);                             \
    float acc = 0.f;                                                            \
    FC2_LOADG(R, CT[2], CT[3]);                                                 \
    SUM8(acc, P);                                                               \
    SUM8(acc, R);                                                               \
    if (__builtin_expect(ng_ > 2, 0)) {   /* rare: hidden rate is low */        \
      const u32x4* Ls_ = (const u32x4*)(list2 + (bt + t_ - 1) * LSTRIDE);       \
      for (int g = 2; g < ng_; ++g) {                                           \
        u32x4 x0 = Ls_[2 * g], x1 = Ls_[2 * g + 1];                             \
        FC2_LOADG(R, x0, x1);                                                   \
        SUM8(acc, R);                                                           \
      }                                                                         \
    }                                                                           \
    FC2_JOIN(RT, cw_);                                                          \
    FC2_LOADG(P, RT[0], RT[1]);   /* entries 0..15 of next body's list */       \
    acc += __shfl_xor(acc, 32, 64);   /* even+odd halves, commutative */        \
    {                                                                           \
      int want_ = t_ - 1;                                                       \
      for (;;) {                                                                \
        int fl_ = *flPart;                                                      \
        if (fl_ >= want_) break;                                                \
        __builtin_amdgcn_s_sleep(1);                                            \
      }                                                                         \
      LDS_FENCE();                                                              \
      float2 sv_ = stPart[lane];                                                \
      float cur_ = A_I * sv_.x + WSC * acc;                                     \
      float vol_ = A_V * sv_.y + cur_;                                          \
      bool s_ = vol_ >= THETA;                                                  \
      vol_ = s_ ? 0.f : vol_;                                                   \
      stMine[lane] = make_float2(cur_, vol_);                                   \
      int p_ = t_ + 1;                                                          \
      int pos_ = p_ & 15;                                                       \
      if (s_) sm |= 1u << pos_;                                                 \
      uint32_t myw_ = sm;                                                       \
      bool isLast_ = (pos_ == lastpos);                                         \
      if (isLast_) {                                                            \
        if (lane < 32) smwMine[col] = myw_;                                     \
        sm = 0;                                                                 \
      }                                                                         \
      LDS_FENCE();                                                              \
      if (lane == 0) *flMine = t_;                                              \
      if (par == 2 && isLast_) {    /* pos 15: flush the 16-p window */         \
        uint32_t w_ = myw_ | smw0[col] | smw1[col] | smw3[col];                 \
        if (lane < 32) {                                                        \
          float vb[16];                                                         \
          _Pragma("unroll")                                                     \
          for (int q = 0; q < 16; ++q) vb[q] = ((w_ >> q) & 1u) ? 1.0f : 0.0f;  \
          float4* dst = (float4*)(op + (p_ - 15));                              \
          dst[0] = make_float4(vb[0],  vb[1],  vb[2],  vb[3]);                  \
          dst[1] = make_float4(vb[4],  vb[5],  vb[6],  vb[7]);                  \
          dst[2] = make_float4(vb[8],  vb[9],  vb[10], vb[11]);                 \
          dst[3] = make_float4(vb[12], vb[13], vb[14], vb[15]);                 \
        }                                                                       \
      }                                                                         \
    }                                                                           \
    cntC = (int)cw_;                                                            \
  } while (0)

  // 256 bodies per wave: t = par, par+4, ..., par+1020 (par3's last body
  // t=1023 is the benign dummy).
  for (int k = 0; k < 128; ++k) {
    FC2_BODY(par + 8 * k,     ct, rt);
    FC2_BODY(par + 8 * k + 4, rt, ct);
  }
#undef FC2_BODY
#undef FC2_LOADG
#undef FC2_JOIN
}

// ---------------------------------------------------------------------------
// ws layout (bytes): bits1 u32[64K*16] @0 (4MB); cnt1 @4194304 (256KB);
// list1 u16[64K*128] @4456448 (16MB); bits2 u64[64K*16] @21233664 (8MB);
// cnt2 @29622272 (256KB); list2 @29884416 (16MB).
// ---------------------------------------------------------------------------
extern "C" void kernel_launch(void* const* d_in, const int* in_sizes, int n_in,
                              void* d_out, int out_size, void* d_ws, size_t ws_size,
                              hipStream_t stream) {
  const float* x  = (const float*)d_in[0];
  const float* w1 = (const float*)d_in[1];
  const float* w2 = (const float*)d_in[2];
  float* out = (float*)d_out;

  char* ws = (char*)d_ws;
  uint32_t* bits1 = (uint32_t*)(ws);
  uint32_t* cnt1  = (uint32_t*)(ws + 4194304);
  uint16_t* list1 = (uint16_t*)(ws + 4456448);
  uint64_t* bits2 = (uint64_t*)(ws + 21233664);
  uint32_t* cnt2  = (uint32_t*)(ws + 29622272);
  uint16_t* list2 = (uint16_t*)(ws + 29884416);

  const int LDS1 = (513 * 64 + 2048 + 16) * 4;         // 139584
  const int LDS2 = (32800 + 2048 + 16 + 512) * 4;      // 141504
  (void)hipFuncSetAttribute((const void*)k_fc1,
      hipFuncAttributeMaxDynamicSharedMemorySize, LDS1);
  (void)hipFuncSetAttribute((const void*)k_fc2,
      hipFuncAttributeMaxDynamicSharedMemorySize, LDS2);

  k_bits1 <<<NB * 16 * 4, 256, 0, stream>>>(x, bits1);
  k_extract<<<(NB * NT) / 256, 256, 0, stream>>>((const uint64_t*)bits1, cnt1,
                                                 list1, 8, NIN << 6, 6);
  k_fc1   <<<16 * 16, 1024, LDS1, stream>>>(w1, cnt1, list1, bits2);
  k_extract<<<(NB * NT) / 256, 256, 0, stream>>>((const uint64_t*)bits2, cnt2,
                                                 list2, 16, NHID << 5, 5);
  k_fc2   <<<16 * 16, 1024, LDS2, stream>>>(w2, cnt2, list2, out);
}